// Round 5
// baseline (461.615 us; speedup 1.0000x reference)
//
#include <hip/hip_runtime.h>

typedef __bf16 bf16;
typedef bf16 bf16x4 __attribute__((ext_vector_type(4)));
typedef bf16 bf16x8 __attribute__((ext_vector_type(8)));
typedef float floatx4 __attribute__((ext_vector_type(4)));
typedef short short4i __attribute__((ext_vector_type(4)));

#define NB 8
#define NQ 1024
#define NK 1024
#define DIM 512
#define NH 8
#define DH 64

// async global->LDS, 16B per lane. LDS dest must be wave-uniform base + lane*16B.
__device__ __forceinline__ void async16(const void* g, void* l) {
    __builtin_amdgcn_global_load_lds(
        (const __attribute__((address_space(1))) unsigned int*)(unsigned long long)(g),
        (__attribute__((address_space(3))) unsigned int*)(unsigned long long)(l),
        16, 0, 0);
}

// 16x16x16 bf16 MFMA (K=16). B-frag k-layout (quad*4+j) matches the S^T
// C-layout (row=quad*4+r) -> P feeds PV in-register with zero shuffles.
__device__ __forceinline__ floatx4 mfma_16x16x16(bf16x4 a, bf16x4 b, floatx4 c) {
#if __has_builtin(__builtin_amdgcn_mfma_f32_16x16x16_bf16)
    return __builtin_amdgcn_mfma_f32_16x16x16_bf16(a, b, c, 0, 0, 0);
#elif __has_builtin(__builtin_amdgcn_mfma_f32_16x16x16bf16_1k)
    return __builtin_amdgcn_mfma_f32_16x16x16bf16_1k(
        __builtin_bit_cast(short4i, a), __builtin_bit_cast(short4i, b), c, 0, 0, 0);
#else
    asm volatile("v_mfma_f32_16x16x16_bf16 %0, %1, %2, %0\n\ts_nop 7\n\ts_nop 7"
                 : "+v"(c) : "v"(a), "v"(b));
    return c;
#endif
}

// ---------------------------------------------------------------------------
// prep_fused: blocks [0,4096): cast Q,K fp32->bf16 (float4 vectorized);
//             blocks [4096,4352): Wt[w][n][k] = (bf16)W[k][n], LDS 64x64 tiles.
// ---------------------------------------------------------------------------
__global__ __launch_bounds__(256) void prep_fused(
    const float* __restrict__ Q, const float* __restrict__ K,
    const float* __restrict__ Wq, const float* __restrict__ Wk,
    const float* __restrict__ Wv, const float* __restrict__ Wo,
    bf16* __restrict__ Qb, bf16* __restrict__ Kb, bf16* __restrict__ Wt)
{
    __shared__ bf16 Tl[64][68];
    const int bid = blockIdx.x;
    if (bid < 4096) {
        const int i = bid * 256 + threadIdx.x;   // float4 index
        float4 a = ((const float4*)Q)[i];
        float4 c = ((const float4*)K)[i];
        bf16x4 qa = {(bf16)a.x, (bf16)a.y, (bf16)a.z, (bf16)a.w};
        bf16x4 ka = {(bf16)c.x, (bf16)c.y, (bf16)c.z, (bf16)c.w};
        *(bf16x4*)(Qb + (size_t)i * 4) = qa;
        *(bf16x4*)(Kb + (size_t)i * 4) = ka;
    } else {
        const int bid2 = bid - 4096;
        const int w = bid2 >> 6;
        const int bx = bid2 & 7, by = (bid2 >> 3) & 7;
        const float* W = (w == 0) ? Wq : (w == 1) ? Wk : (w == 2) ? Wv : Wo;
        bf16* out = Wt + (size_t)w * DIM * DIM;
        const int k0 = bx * 64, n0 = by * 64;
        const int tx = threadIdx.x & 15, ty = threadIdx.x >> 4;
        for (int pass = 0; pass < 4; ++pass) {
            int k = ty + pass * 16;
            float4 v = *(const float4*)&W[(size_t)(k0 + k) * DIM + n0 + tx * 4];
            Tl[tx * 4 + 0][k] = (bf16)v.x;
            Tl[tx * 4 + 1][k] = (bf16)v.y;
            Tl[tx * 4 + 2][k] = (bf16)v.z;
            Tl[tx * 4 + 3][k] = (bf16)v.w;
        }
        __syncthreads();
        for (int pass = 0; pass < 4; ++pass) {
            int n = ty + pass * 16;
            bf16x4 ov = *(const bf16x4*)&Tl[n][tx * 4];
            *(bf16x4*)&out[(size_t)(n0 + n) * DIM + k0 + tx * 4] = ov;
        }
    }
}

// ---------------------------------------------------------------------------
// proj_fused: 128x64 tiles (M=128, N=64), BK=64, XOR-swizzled async staging,
// m-minor block mapping. LDS 48 KB -> 3 blocks/CU. Grid 1536 = 6/CU in two
// full rounds, 3 waves/SIMD. Wave grid 2x2, wave tile 64x32, acc[4][2].
// blocks [0,512):    Q proj -> Qp head layout [b,h,q,64], PRE-SCALED by
//                    SC = 1/(sqrt(64)*0.1)*log2(e) so attn S is exp2-ready.
// blocks [512,1536): KV proj: n<512 -> Kp head layout; n>=512 -> Vpt
//                    [b,h,d,1024] via in-LDS transpose (coalesced stores).
// ---------------------------------------------------------------------------
__global__ __launch_bounds__(256) void proj_fused(
    const bf16* __restrict__ Qb, const bf16* __restrict__ Kb,
    const bf16* __restrict__ Wt,
    const float* __restrict__ bq, const float* __restrict__ bk,
    const float* __restrict__ bv,
    bf16* __restrict__ Qp, bf16* __restrict__ Kp, bf16* __restrict__ Vpt)
{
    // 48 KB: A0(16K) | A1(16K) | B0(8K) | B1(8K)   (bf16 units: 8192|8192|4096|4096)
    __shared__ __attribute__((aligned(16))) bf16 sh[24576];
    const int t = threadIdx.x;
    const int wave = t >> 6, lane = t & 63, quad = lane >> 4, l16 = lane & 15;
    const int wr = wave >> 1, wc = wave & 1;
    const int bid = blockIdx.x;
    const bool isQ = bid < 512;
    const bf16* A; const bf16* W; int m0, n0;
    if (isQ) { A = Qb; W = Wt;             m0 = (bid & 63) * 128;  n0 = (bid >> 6) * 64; }
    else     { int b2 = bid - 512;
               A = Kb; W = Wt + 512 * DIM; m0 = (b2 & 63) * 128;   n0 = (b2 >> 6) * 64; }

    const int r1 = t >> 3, s1 = t & 7;
    const int p1 = s1 ^ (r1 & 7);          // rows r1+32j keep row&7
    const bf16* aSrc = A + (size_t)(m0 + r1) * DIM + p1 * 8;
    const bf16* wSrc = W + (size_t)(n0 + r1) * DIM + p1 * 8;

    floatx4 acc[4][2];
    for (int i = 0; i < 4; ++i)
        for (int j = 0; j < 2; ++j) acc[i][j] = (floatx4){0.f, 0.f, 0.f, 0.f};

    // prologue: issue kt=0 into buf 0
    #pragma unroll
    for (int j = 0; j < 4; ++j)
        async16(aSrc + (size_t)j * 32 * DIM, sh + (t + j * 256) * 8);
    #pragma unroll
    for (int j = 0; j < 2; ++j)
        async16(wSrc + (size_t)j * 32 * DIM, sh + 16384 + (t + j * 256) * 8);

    for (int kt = 0; kt < 8; ++kt) {
        __syncthreads();   // tile kt loads done; all waves done with other buf
        const int cur = kt & 1;
        bf16* Acur = sh + cur * 8192;
        bf16* Bcur = sh + 16384 + cur * 4096;
        if (kt < 7) {
            bf16* Anxt = sh + (1 - cur) * 8192;
            bf16* Bnxt = sh + 16384 + (1 - cur) * 4096;
            const int ko = (kt + 1) * 64;
            #pragma unroll
            for (int j = 0; j < 4; ++j)
                async16(aSrc + ko + (size_t)j * 32 * DIM, Anxt + (t + j * 256) * 8);
            #pragma unroll
            for (int j = 0; j < 2; ++j)
                async16(wSrc + ko + (size_t)j * 32 * DIM, Bnxt + (t + j * 256) * 8);
        }
        #pragma unroll
        for (int ks = 0; ks < 2; ++ks) {
            bf16x8 af[4], bfr[2];
            #pragma unroll
            for (int mi = 0; mi < 4; ++mi) {
                const int row = wr * 64 + mi * 16 + l16;
                af[mi] = *(const bf16x8*)(Acur + row * 64 + (((ks * 4 + quad) ^ (row & 7)) << 3));
            }
            #pragma unroll
            for (int ni = 0; ni < 2; ++ni) {
                const int row = wc * 32 + ni * 16 + l16;
                bfr[ni] = *(const bf16x8*)(Bcur + row * 64 + (((ks * 4 + quad) ^ (row & 7)) << 3));
            }
            #pragma unroll
            for (int mi = 0; mi < 4; ++mi)
                #pragma unroll
                for (int ni = 0; ni < 2; ++ni)
                    acc[mi][ni] = __builtin_amdgcn_mfma_f32_16x16x32_bf16(
                        af[mi], bfr[ni], acc[mi][ni], 0, 0, 0);
        }
    }

    const bool isV = (!isQ) && (n0 >= 512);
    if (!isV) {
        bf16* out = isQ ? Qp : Kp;
        const float* bias = isQ ? bq : bk;
        const float qscale = isQ ? 1.8033688f : 1.0f;   // SC folded into Qp
        for (int ni = 0; ni < 2; ++ni) {
            const int n = n0 + wc * 32 + ni * 16 + l16;
            const float bb = bias[n];
            const int hd = n >> 6, d = n & 63;
            for (int mi = 0; mi < 4; ++mi) {
                for (int r = 0; r < 4; ++r) {
                    const int m = m0 + wr * 64 + mi * 16 + quad * 4 + r;
                    const int b = m >> 10, q = m & 1023;
                    out[((size_t)(b * 8 + hd) * 1024 + q) * 64 + d] =
                        (bf16)((acc[mi][ni][r] + bb) * qscale);
                }
            }
        }
    } else {
        // dump tile (+bias) to LDS as Tb[n][m] (n local 0..63, 16 KB) with
        // chunk-XOR swizzle, then store coalesced rows of Vpt [b,h,d,1024]
        __syncthreads();
        for (int ni = 0; ni < 2; ++ni) {
            const int n = wc * 32 + ni * 16 + l16;           // local n 0..63
            const float bb = bv[n0 + n - 512];
            for (int mi = 0; mi < 4; ++mi) {
                const int mb = wr * 64 + mi * 16 + quad * 4;  // local m base (r=0..3)
                const int slot = ((mb >> 3) ^ (n & 15));
                bf16x4 pk = {(bf16)(acc[mi][ni][0] + bb), (bf16)(acc[mi][ni][1] + bb),
                             (bf16)(acc[mi][ni][2] + bb), (bf16)(acc[mi][ni][3] + bb)};
                *(bf16x4*)(sh + n * 128 + slot * 8 + (mb & 7)) = pk;
            }
        }
        __syncthreads();
        const int n = t >> 2, hf = t & 3;                     // 4 threads/row
        const int nv = n0 + n - 512, hd = nv >> 6, d = nv & 63;
        const int b = m0 >> 10, qb = m0 & 1023;
        bf16* dst = Vpt + ((size_t)(b * 8 + hd) * 64 + d) * 1024 + qb;
        #pragma unroll
        for (int j = 0; j < 4; ++j) {
            const int ch = hf * 4 + j;                        // 16 chunks of 8 m
            const int slot = ch ^ (n & 15);
            bf16x8 v8 = *(const bf16x8*)(sh + n * 128 + slot * 8);
            *(bf16x8*)(dst + ch * 8) = v8;
        }
    }
}

// ---------------------------------------------------------------------------
// attn: flash attention per (b,h). 1024 blocks x 4 waves, 64 q/block.
// SPLIT-KEY: wave w owns keys [w*16, w*16+16) of each 64-key tile, ALL 64 q.
// QK^T: S^T = K Q^T via 16x16x32 (A = K rows = wave's keys, B = Q in regs).
// S^T C-layout (row=key quad*4+r, col=q l16) IS the 16x16x16 B-frag layout
// -> P feeds PV (O^T = V^T P^T) entirely in-register: no P LDS round-trip.
// Per wave/kt LDS: 2 b128 (K) + 4 b64 (V) = 5x less than q-split.
// Denominator in VALU (idle pipe); cross-wave O^T reduction via LDS slices
// at the end + transposed LDS pass for coalesced stores.
// Q pre-scaled in proj -> P = exp2(S). Mask: ballot fast path.
// ---------------------------------------------------------------------------
__global__ __launch_bounds__(256, 3) void attn_kernel(
    const bf16* __restrict__ Qp, const bf16* __restrict__ Kp,
    const bf16* __restrict__ Vpt, const int* __restrict__ mask,
    bf16* __restrict__ Oa)
{
    const int bh = blockIdx.x & 63, qblk = blockIdx.x >> 6;  // qblk 0..15
    const int b = bh >> 3, hd = bh & 7;
    const int t = threadIdx.x;
    const int wave = t >> 6, lane = t & 63, quad = lane >> 4, l16 = lane & 15;

    // KV: K dbuf (2x8KB) | V dbuf (2x8KB) = 32 KB; reused post-loop as
    // fp32 reduction slices (8 x 4KB) and bf16 O^T transpose buffer.
    __shared__ __attribute__((aligned(16))) bf16 KV[16384];
    __shared__ float Ls[4][64];

    const bf16* Qbase = Qp + ((size_t)bh * NQ + qblk * 64) * DH;
    const bf16* Kbase = Kp + (size_t)bh * NK * DH;
    const bf16* Vbase = Vpt + (size_t)bh * DH * NK;
    const int* mrow = mask + b * NK;

    // Q B-frags: ALL 64 q of the block (qg = q>>4), full d (hh halves)
    bf16x8 qf[4][2];
    #pragma unroll
    for (int qg = 0; qg < 4; ++qg)
        #pragma unroll
        for (int hh = 0; hh < 2; ++hh)
            qf[qg][hh] = *(const bf16x8*)(Qbase + (size_t)(qg * 16 + l16) * DH + hh * 32 + quad * 8);

    // O^T acc: o[dsub][qg] -> O^T[d = dsub*16 + quad*4 + r][q = qg*16 + l16]
    floatx4 o[4][4];
    float lsum[4] = {0.f, 0.f, 0.f, 0.f};
    #pragma unroll
    for (int i = 0; i < 4; ++i)
        #pragma unroll
        for (int j = 0; j < 4; ++j) o[i][j] = (floatx4){0.f, 0.f, 0.f, 0.f};

    const int r1 = t >> 3, s1 = t & 7;
    const int p1 = s1 ^ (r1 & 7);          // (r1+32)&7 == r1&7
    const bf16* kSrc = Kbase + r1 * 64 + p1 * 8;            // + kt*4096
    const bf16* vSrc = Vbase + (size_t)r1 * 1024 + p1 * 8;  // + kt*64

    // prologue: issue tile 0 into buf 0  (K at KV+0, V at KV+8192)
    async16(kSrc, KV + t * 8);
    async16(kSrc + 32 * 64, KV + (t + 256) * 8);
    async16(vSrc, KV + 8192 + t * 8);
    async16(vSrc + (size_t)32 * 1024, KV + 8192 + (t + 256) * 8);

    const int rowk = wave * 16 + l16;      // this wave's key row in the tile
    for (int kt = 0; kt < NK / 64; ++kt) {
        __syncthreads();   // tile kt loads complete; all waves done with other buf
        const int cur = kt & 1;
        bf16* Ktc = KV + cur * 4096;
        bf16* Vtc = KV + 8192 + cur * 4096;
        if (kt < NK / 64 - 1) {
            const int nxt = 1 - cur;
            async16(kSrc + (kt + 1) * 4096, KV + nxt * 4096 + t * 8);
            async16(kSrc + (kt + 1) * 4096 + 32 * 64, KV + nxt * 4096 + (t + 256) * 8);
            async16(vSrc + (kt + 1) * 64, KV + 8192 + nxt * 4096 + t * 8);
            async16(vSrc + (kt + 1) * 64 + (size_t)32 * 1024, KV + 8192 + nxt * 4096 + (t + 256) * 8);
        }

        // K A-frags: only this wave's 16 key rows (2 b128, conflict-free)
        bf16x8 kb0 = *(const bf16x8*)(Ktc + rowk * 64 + ((quad ^ (rowk & 7)) << 3));
        bf16x8 kb1 = *(const bf16x8*)(Ktc + rowk * 64 + (((quad + 4) ^ (rowk & 7)) << 3));

        // S^T = K Q^T: C col = q (l16), row = key quad*4+r (wave's keys)
        floatx4 sf[4];
        __builtin_amdgcn_s_setprio(1);
        #pragma unroll
        for (int qg = 0; qg < 4; ++qg) {
            floatx4 s = {0.f, 0.f, 0.f, 0.f};
            s = __builtin_amdgcn_mfma_f32_16x16x32_bf16(kb0, qf[qg][0], s, 0, 0, 0);
            s = __builtin_amdgcn_mfma_f32_16x16x32_bf16(kb1, qf[qg][1], s, 0, 0, 0);
            sf[qg] = s;
        }
        __builtin_amdgcn_s_setprio(0);

        // mask: wave-uniform fast path (1 dword/lane + ballot per 64-key tile)
        const int mv = mrow[kt * 64 + lane];
        if (!__all(mv != 0)) {
            const int4 m4 = *(const int4*)&mrow[kt * 64 + wave * 16 + quad * 4];
            #pragma unroll
            for (int qg = 0; qg < 4; ++qg) {
                if (!m4.x) sf[qg][0] = -3.0e38f;
                if (!m4.y) sf[qg][1] = -3.0e38f;
                if (!m4.z) sf[qg][2] = -3.0e38f;
                if (!m4.w) sf[qg][3] = -3.0e38f;
            }
        }
        // P = exp2(S) (scale pre-folded into Qp); VALU row-sum; pack to B-frag
        bf16x4 pb[4];
        #pragma unroll
        for (int qg = 0; qg < 4; ++qg) {
            const float e0 = __builtin_amdgcn_exp2f(sf[qg][0]);
            const float e1 = __builtin_amdgcn_exp2f(sf[qg][1]);
            const float e2 = __builtin_amdgcn_exp2f(sf[qg][2]);
            const float e3 = __builtin_amdgcn_exp2f(sf[qg][3]);
            lsum[qg] += (e0 + e1) + (e2 + e3);
            pb[qg] = (bf16x4){(bf16)e0, (bf16)e1, (bf16)e2, (bf16)e3};
        }
        // PV: O^T[d][q] += V^T[d][wave's 16 keys] * P^T  (x16, P in-register)
        __builtin_amdgcn_s_setprio(1);
        #pragma unroll
        for (int dsub = 0; dsub < 4; ++dsub) {
            const int d = dsub * 16 + l16;
            bf16x4 av = *(const bf16x4*)(Vtc + d * 64 +
                                         (((wave * 4 + quad) ^ ((d & 7) << 1)) << 2));
            #pragma unroll
            for (int qg = 0; qg < 4; ++qg)
                o[dsub][qg] = mfma_16x16x16(av, pb[qg], o[dsub][qg]);
        }
        __builtin_amdgcn_s_setprio(0);
    }

    // ---- epilogue: cross-wave reduce O^T (d-slice ownership) + denominator ----
    __syncthreads();                                   // B1: KV tiles free
    float* scr = (float*)KV;                           // 8 slices x 1024 fp32 (4KB)

    #pragma unroll
    for (int qg = 0; qg < 4; ++qg) {
        lsum[qg] += __shfl_xor(lsum[qg], 16, 64);
        lsum[qg] += __shfl_xor(lsum[qg], 32, 64);
    }
    if (quad == 0)
        #pragma unroll
        for (int qg = 0; qg < 4; ++qg) Ls[wave][qg * 16 + l16] = lsum[qg];

    {   // round 1: send slices for dsub (wave+1)&3 and (wave+2)&3
        const int rA = (wave + 1) & 3, rB = (wave + 2) & 3;
        float* sA = scr + (rA * 2 + 0) * 1024;
        float* sB = scr + (rB * 2 + 1) * 1024;
        #pragma unroll
        for (int qg = 0; qg < 4; ++qg) {
            const int q = qg * 16 + l16, cs = quad ^ (l16 & 3);
            *(floatx4*)(sA + q * 16 + cs * 4) = o[rA][qg];
            *(floatx4*)(sB + q * 16 + cs * 4) = o[rB][qg];
        }
    }
    __syncthreads();                                   // B2
    float inv[4];
    #pragma unroll
    for (int qg = 0; qg < 4; ++qg) {
        const int q = qg * 16 + l16;
        inv[qg] = 1.f / (Ls[0][q] + Ls[1][q] + Ls[2][q] + Ls[3][q]);
    }
    {   // receive 2 partials for own dsub
        float* sA = scr + (wave * 2 + 0) * 1024;
        float* sB = scr + (wave * 2 + 1) * 1024;
        #pragma unroll
        for (int qg = 0; qg < 4; ++qg) {
            const int q = qg * 16 + l16, cs = quad ^ (l16 & 3);
            o[wave][qg] += *(const floatx4*)(sA + q * 16 + cs * 4);
            o[wave][qg] += *(const floatx4*)(sB + q * 16 + cs * 4);
        }
    }
    __syncthreads();                                   // B3
    {   // round 2: send slice for dsub (wave+3)&3
        const int rC = (wave + 3) & 3;
        float* sC = scr + (rC * 2 + 0) * 1024;
        #pragma unroll
        for (int qg = 0; qg < 4; ++qg) {
            const int q = qg * 16 + l16, cs = quad ^ (l16 & 3);
            *(floatx4*)(sC + q * 16 + cs * 4) = o[rC][qg];
        }
    }
    __syncthreads();                                   // B4
    {
        float* sC = scr + (wave * 2 + 0) * 1024;
        #pragma unroll
        for (int qg = 0; qg < 4; ++qg) {
            const int q = qg * 16 + l16, cs = quad ^ (l16 & 3);
            o[wave][qg] += *(const floatx4*)(sC + q * 16 + cs * 4);
        }
    }
    __syncthreads();                                   // B5: scr free again
    // normalize own d-slice, write transposed bf16 O^T[q][d] (chunk-XOR q&7)
    {
        bf16* Ot = KV;
        #pragma unroll
        for (int qg = 0; qg < 4; ++qg) {
            const int q = qg * 16 + l16;
            const int chunk = (wave * 2 + (quad >> 1)) ^ (q & 7);
            bf16x4 pk = {(bf16)(o[wave][qg][0] * inv[qg]), (bf16)(o[wave][qg][1] * inv[qg]),
                         (bf16)(o[wave][qg][2] * inv[qg]), (bf16)(o[wave][qg][3] * inv[qg])};
            *(bf16x4*)(Ot + q * 64 + chunk * 8 + (quad & 1) * 4) = pk;
        }
    }
    __syncthreads();                                   // B6
    {   // coalesced store: 4 threads/row, 2 x b128 each
        const bf16* Ot = KV;
        const int q = t >> 2, cp = t & 3;
        bf16* orow = Oa + ((size_t)(b * NQ + qblk * 64 + q)) * DIM + hd * 64;
        #pragma unroll
        for (int i = 0; i < 2; ++i) {
            const int c = cp * 2 + i;
            bf16x8 v = *(const bf16x8*)(Ot + q * 64 + (c ^ (q & 7)) * 8);
            *(bf16x8*)(orow + c * 8) = v;
        }
    }
}

// ---------------------------------------------------------------------------
// ffn_gemm: 128x64 tiles (M=128, N=64), BK=64, XOR-swizzled staging,
// m-minor mapping, K-loop double-buffer. Grid 512, LDS 48 KB.
// Yb (bf16) = Oa + relu(Oa @ Wo^T + bo).
// ---------------------------------------------------------------------------
__global__ __launch_bounds__(256) void ffn_gemm(
    const bf16* __restrict__ Oa, const bf16* __restrict__ W,
    const float* __restrict__ bias, bf16* __restrict__ Yb)
{
    __shared__ __attribute__((aligned(16))) bf16 sh[24576];  // 48 KB: A0|A1|B0|B1
    const int t = threadIdx.x;
    const int wave = t >> 6, lane = t & 63, quad = lane >> 4, l16 = lane & 15;
    const int wr = wave >> 1, wc = wave & 1;
    const int m0 = (blockIdx.x & 63) * 128, n0 = (blockIdx.x >> 6) * 64;

    const int r1 = t >> 3, s1 = t & 7;
    const int p1 = s1 ^ (r1 & 7);
    const bf16* aSrc = Oa + (size_t)(m0 + r1) * DIM + p1 * 8;
    const bf16* wSrc = W  + (size_t)(n0 + r1) * DIM + p1 * 8;

    floatx4 acc[4][2];
    for (int i = 0; i < 4; ++i)
        for (int j = 0; j < 2; ++j) acc[i][j] = (floatx4){0.f, 0.f, 0.f, 0.f};

    #pragma unroll
    for (int j = 0; j < 4; ++j)
        async16(aSrc + (size_t)j * 32 * DIM, sh + (t + j * 256) * 8);
    #pragma unroll
    for (int j = 0; j < 2; ++j)
        async16(wSrc + (size_t)j * 32 * DIM, sh + 16384 + (t + j * 256) * 8);

    for (int kt = 0; kt < 8; ++kt) {
        __syncthreads();
        const int cur = kt & 1;
        bf16* Acur = sh + cur * 8192;
        bf16* Bcur = sh + 16384 + cur * 4096;
        if (kt < 7) {
            bf16* Anxt = sh + (1 - cur) * 8192;
            bf16* Bnxt = sh + 16384 + (1 - cur) * 4096;
            const int ko = (kt + 1) * 64;
            #pragma unroll
            for (int j = 0; j < 4; ++j)
                async16(aSrc + ko + (size_t)j * 32 * DIM, Anxt + (t + j * 256) * 8);
            #pragma unroll
            for (int j = 0; j < 2; ++j)
                async16(wSrc + ko + (size_t)j * 32 * DIM, Bnxt + (t + j * 256) * 8);
        }
        #pragma unroll
        for (int ks = 0; ks < 2; ++ks) {
            bf16x8 af[4], bfr[2];
            #pragma unroll
            for (int mi = 0; mi < 4; ++mi) {
                const int row = wr * 64 + mi * 16 + l16;
                af[mi] = *(const bf16x8*)(Acur + row * 64 + (((ks * 4 + quad) ^ (row & 7)) << 3));
            }
            #pragma unroll
            for (int ni = 0; ni < 2; ++ni) {
                const int row = wc * 32 + ni * 16 + l16;
                bfr[ni] = *(const bf16x8*)(Bcur + row * 64 + (((ks * 4 + quad) ^ (row & 7)) << 3));
            }
            #pragma unroll
            for (int mi = 0; mi < 4; ++mi)
                #pragma unroll
                for (int ni = 0; ni < 2; ++ni)
                    acc[mi][ni] = __builtin_amdgcn_mfma_f32_16x16x32_bf16(
                        af[mi], bfr[ni], acc[mi][ni], 0, 0, 0);
        }
    }

    for (int ni = 0; ni < 2; ++ni) {
        const int n = n0 + wc * 32 + ni * 16 + l16;
        const float bb = bias[n];
        for (int mi = 0; mi < 4; ++mi) {
            for (int r = 0; r < 4; ++r) {
                const int m = m0 + wr * 64 + mi * 16 + quad * 4 + r;
                const float ov = (float)Oa[(size_t)m * DIM + n];
                Yb[(size_t)m * DIM + n] = (bf16)(ov + fmaxf(acc[mi][ni][r] + bb, 0.f));
            }
        }
    }
}

// ---------------------------------------------------------------------------
// ln: LayerNorm over last dim (512). One wave per row; bf16 in, fp32 out.
// ---------------------------------------------------------------------------
__global__ __launch_bounds__(256) void ln_kernel(
    const bf16* __restrict__ Y, const float* __restrict__ gamma,
    const float* __restrict__ beta, float* __restrict__ out)
{
    const int row  = blockIdx.x * 4 + (threadIdx.x >> 6);
    const int lane = threadIdx.x & 63;
    bf16x8 v = *(const bf16x8*)(Y + (size_t)row * DIM + lane * 8);
    float f[8];
    float s = 0.f, sq = 0.f;
    #pragma unroll
    for (int j = 0; j < 8; ++j) {
        f[j] = (float)v[j];
        s += f[j];
        sq += f[j] * f[j];
    }
    for (int mk = 32; mk >= 1; mk >>= 1) {
        s  += __shfl_xor(s,  mk, 64);
        sq += __shfl_xor(sq, mk, 64);
    }
    const float mu  = s * (1.f / 512.f);
    const float var = sq * (1.f / 512.f) - mu * mu;
    const float inv = rsqrtf(var + 1e-5f);
    float4 g1 = ((const float4*)gamma)[lane * 2];
    float4 g2 = ((const float4*)gamma)[lane * 2 + 1];
    float4 b1 = ((const float4*)beta)[lane * 2];
    float4 b2 = ((const float4*)beta)[lane * 2 + 1];
    float4 o1, o2;
    o1.x = (f[0] - mu) * inv * g1.x + b1.x;
    o1.y = (f[1] - mu) * inv * g1.y + b1.y;
    o1.z = (f[2] - mu) * inv * g1.z + b1.z;
    o1.w = (f[3] - mu) * inv * g1.w + b1.w;
    o2.x = (f[4] - mu) * inv * g2.x + b2.x;
    o2.y = (f[5] - mu) * inv * g2.y + b2.y;
    o2.z = (f[6] - mu) * inv * g2.z + b2.z;
    o2.w = (f[7] - mu) * inv * g2.w + b2.w;
    float* orow = out + (size_t)row * DIM;
    ((float4*)orow)[lane * 2]     = o1;
    ((float4*)orow)[lane * 2 + 1] = o2;
}

// ---------------------------------------------------------------------------
extern "C" void kernel_launch(void* const* d_in, const int* in_sizes, int n_in,
                              void* d_out, int out_size, void* d_ws, size_t ws_size,
                              hipStream_t stream) {
    const float* Q  = (const float*)d_in[0];
    const float* K  = (const float*)d_in[1];
    const int*   mask = (const int*)d_in[2];
    const float* Wq = (const float*)d_in[3];
    const float* bq = (const float*)d_in[4];
    const float* Wk = (const float*)d_in[5];
    const float* bk = (const float*)d_in[6];
    const float* Wv = (const float*)d_in[7];
    const float* bv = (const float*)d_in[8];
    const float* Wo = (const float*)d_in[9];
    const float* bo = (const float*)d_in[10];
    const float* gamma = (const float*)d_in[11];
    const float* beta  = (const float*)d_in[12];

    char* ws = (char*)d_ws;
    bf16* Wt  = (bf16*)(ws);                   // 2 MB (4 x 512x512 bf16, transposed)
    bf16* Qb  = (bf16*)(ws + 2097152);         // 8 MB
    bf16* Kb  = (bf16*)(ws + 10485760);        // 8 MB
    bf16* Qp  = (bf16*)(ws + 18874368);        // 8 MB  [b,h,q,64] (pre-scaled)
    bf16* Kp  = (bf16*)(ws + 27262976);        // 8 MB  [b,h,k,64]
    bf16* Vpt = (bf16*)(ws + 35651584);        // 8 MB  [b,h,d,1024]
    bf16* Oa  = (bf16*)(ws + 44040192);        // 8 MB  [b,q,512]
    bf16* Yb  = (bf16*)(ws + 52428800);        // 8 MB  [b,q,512] bf16
    float* out = (float*)d_out;

    prep_fused<<<4352, 256, 0, stream>>>(Q, K, Wq, Wk, Wv, Wo, Qb, Kb, Wt);
    proj_fused<<<1536, 256, 0, stream>>>(Qb, Kb, Wt, bq, bk, bv, Qp, Kp, Vpt);
    attn_kernel<<<1024, 256, 0, stream>>>(Qp, Kp, Vpt, mask, Oa);
    ffn_gemm<<<512, 256, 0, stream>>>(Oa, Wt + 3 * 262144, bo, Yb);
    ln_kernel<<<2048, 256, 0, stream>>>(Yb, gamma, beta, out);
}

// Round 6
// 174.178 us; speedup vs baseline: 2.6502x; 2.6502x over previous
//
#include <hip/hip_runtime.h>

typedef __bf16 bf16;
typedef bf16 bf16x4 __attribute__((ext_vector_type(4)));
typedef bf16 bf16x8 __attribute__((ext_vector_type(8)));
typedef float floatx4 __attribute__((ext_vector_type(4)));
typedef short short4i __attribute__((ext_vector_type(4)));

#define NB 8
#define NQ 1024
#define NK 1024
#define DIM 512
#define NH 8
#define DH 64

// async global->LDS, 16B per lane. LDS dest must be wave-uniform base + lane*16B.
__device__ __forceinline__ void async16(const void* g, void* l) {
    __builtin_amdgcn_global_load_lds(
        (const __attribute__((address_space(1))) unsigned int*)(unsigned long long)(g),
        (__attribute__((address_space(3))) unsigned int*)(unsigned long long)(l),
        16, 0, 0);
}

// 16x16x16 bf16 MFMA (K=16). B-frag k-layout (quad*4+j) matches the S^T
// C-layout (row=quad*4+r) -> P feeds PV in-register with zero shuffles.
__device__ __forceinline__ floatx4 mfma_16x16x16(bf16x4 a, bf16x4 b, floatx4 c) {
#if __has_builtin(__builtin_amdgcn_mfma_f32_16x16x16_bf16)
    return __builtin_amdgcn_mfma_f32_16x16x16_bf16(a, b, c, 0, 0, 0);
#elif __has_builtin(__builtin_amdgcn_mfma_f32_16x16x16bf16_1k)
    return __builtin_amdgcn_mfma_f32_16x16x16bf16_1k(
        __builtin_bit_cast(short4i, a), __builtin_bit_cast(short4i, b), c, 0, 0, 0);
#else
    asm volatile("v_mfma_f32_16x16x16_bf16 %0, %1, %2, %0\n\ts_nop 7\n\ts_nop 7"
                 : "+v"(c) : "v"(a), "v"(b));
    return c;
#endif
}

// ---------------------------------------------------------------------------
// prep_fused: blocks [0,4096): cast Q,K fp32->bf16 (float4 vectorized);
//             blocks [4096,4352): Wt[w][n][k] = (bf16)W[k][n], LDS 64x64 tiles.
// ---------------------------------------------------------------------------
__global__ __launch_bounds__(256) void prep_fused(
    const float* __restrict__ Q, const float* __restrict__ K,
    const float* __restrict__ Wq, const float* __restrict__ Wk,
    const float* __restrict__ Wv, const float* __restrict__ Wo,
    bf16* __restrict__ Qb, bf16* __restrict__ Kb, bf16* __restrict__ Wt)
{
    __shared__ bf16 Tl[64][68];
    const int bid = blockIdx.x;
    if (bid < 4096) {
        const int i = bid * 256 + threadIdx.x;   // float4 index
        float4 a = ((const float4*)Q)[i];
        float4 c = ((const float4*)K)[i];
        bf16x4 qa = {(bf16)a.x, (bf16)a.y, (bf16)a.z, (bf16)a.w};
        bf16x4 ka = {(bf16)c.x, (bf16)c.y, (bf16)c.z, (bf16)c.w};
        *(bf16x4*)(Qb + (size_t)i * 4) = qa;
        *(bf16x4*)(Kb + (size_t)i * 4) = ka;
    } else {
        const int bid2 = bid - 4096;
        const int w = bid2 >> 6;
        const int bx = bid2 & 7, by = (bid2 >> 3) & 7;
        const float* W = (w == 0) ? Wq : (w == 1) ? Wk : (w == 2) ? Wv : Wo;
        bf16* out = Wt + (size_t)w * DIM * DIM;
        const int k0 = bx * 64, n0 = by * 64;
        const int tx = threadIdx.x & 15, ty = threadIdx.x >> 4;
        for (int pass = 0; pass < 4; ++pass) {
            int k = ty + pass * 16;
            float4 v = *(const float4*)&W[(size_t)(k0 + k) * DIM + n0 + tx * 4];
            Tl[tx * 4 + 0][k] = (bf16)v.x;
            Tl[tx * 4 + 1][k] = (bf16)v.y;
            Tl[tx * 4 + 2][k] = (bf16)v.z;
            Tl[tx * 4 + 3][k] = (bf16)v.w;
        }
        __syncthreads();
        for (int pass = 0; pass < 4; ++pass) {
            int n = ty + pass * 16;
            bf16x4 ov = *(const bf16x4*)&Tl[n][tx * 4];
            *(bf16x4*)&out[(size_t)(n0 + n) * DIM + k0 + tx * 4] = ov;
        }
    }
}

// ---------------------------------------------------------------------------
// proj_fused: 128x64 tiles (M=128, N=64), BK=64, XOR-swizzled async staging,
// m-minor block mapping. LDS 48 KB -> 3 blocks/CU. Grid 1536 = 6/CU in two
// full rounds, 3 waves/SIMD. Wave grid 2x2, wave tile 64x32, acc[4][2].
// blocks [0,512):    Q proj -> Qp head layout [b,h,q,64], PRE-SCALED by
//                    SC = 1/(sqrt(64)*0.1)*log2(e) so attn S is exp2-ready.
// blocks [512,1536): KV proj: n<512 -> Kp head layout; n>=512 -> Vpt
//                    [b,h,d,1024] via in-LDS transpose (coalesced stores).
// ---------------------------------------------------------------------------
__global__ __launch_bounds__(256) void proj_fused(
    const bf16* __restrict__ Qb, const bf16* __restrict__ Kb,
    const bf16* __restrict__ Wt,
    const float* __restrict__ bq, const float* __restrict__ bk,
    const float* __restrict__ bv,
    bf16* __restrict__ Qp, bf16* __restrict__ Kp, bf16* __restrict__ Vpt)
{
    // 48 KB: A0(16K) | A1(16K) | B0(8K) | B1(8K)   (bf16 units: 8192|8192|4096|4096)
    __shared__ __attribute__((aligned(16))) bf16 sh[24576];
    const int t = threadIdx.x;
    const int wave = t >> 6, lane = t & 63, quad = lane >> 4, l16 = lane & 15;
    const int wr = wave >> 1, wc = wave & 1;
    const int bid = blockIdx.x;
    const bool isQ = bid < 512;
    const bf16* A; const bf16* W; int m0, n0;
    if (isQ) { A = Qb; W = Wt;             m0 = (bid & 63) * 128;  n0 = (bid >> 6) * 64; }
    else     { int b2 = bid - 512;
               A = Kb; W = Wt + 512 * DIM; m0 = (b2 & 63) * 128;   n0 = (b2 >> 6) * 64; }

    const int r1 = t >> 3, s1 = t & 7;
    const int p1 = s1 ^ (r1 & 7);          // rows r1+32j keep row&7
    const bf16* aSrc = A + (size_t)(m0 + r1) * DIM + p1 * 8;
    const bf16* wSrc = W + (size_t)(n0 + r1) * DIM + p1 * 8;

    floatx4 acc[4][2];
    for (int i = 0; i < 4; ++i)
        for (int j = 0; j < 2; ++j) acc[i][j] = (floatx4){0.f, 0.f, 0.f, 0.f};

    // prologue: issue kt=0 into buf 0
    #pragma unroll
    for (int j = 0; j < 4; ++j)
        async16(aSrc + (size_t)j * 32 * DIM, sh + (t + j * 256) * 8);
    #pragma unroll
    for (int j = 0; j < 2; ++j)
        async16(wSrc + (size_t)j * 32 * DIM, sh + 16384 + (t + j * 256) * 8);

    for (int kt = 0; kt < 8; ++kt) {
        __syncthreads();   // tile kt loads done; all waves done with other buf
        const int cur = kt & 1;
        bf16* Acur = sh + cur * 8192;
        bf16* Bcur = sh + 16384 + cur * 4096;
        if (kt < 7) {
            bf16* Anxt = sh + (1 - cur) * 8192;
            bf16* Bnxt = sh + 16384 + (1 - cur) * 4096;
            const int ko = (kt + 1) * 64;
            #pragma unroll
            for (int j = 0; j < 4; ++j)
                async16(aSrc + ko + (size_t)j * 32 * DIM, Anxt + (t + j * 256) * 8);
            #pragma unroll
            for (int j = 0; j < 2; ++j)
                async16(wSrc + ko + (size_t)j * 32 * DIM, Bnxt + (t + j * 256) * 8);
        }
        #pragma unroll
        for (int ks = 0; ks < 2; ++ks) {
            bf16x8 af[4], bfr[2];
            #pragma unroll
            for (int mi = 0; mi < 4; ++mi) {
                const int row = wr * 64 + mi * 16 + l16;
                af[mi] = *(const bf16x8*)(Acur + row * 64 + (((ks * 4 + quad) ^ (row & 7)) << 3));
            }
            #pragma unroll
            for (int ni = 0; ni < 2; ++ni) {
                const int row = wc * 32 + ni * 16 + l16;
                bfr[ni] = *(const bf16x8*)(Bcur + row * 64 + (((ks * 4 + quad) ^ (row & 7)) << 3));
            }
            #pragma unroll
            for (int mi = 0; mi < 4; ++mi)
                #pragma unroll
                for (int ni = 0; ni < 2; ++ni)
                    acc[mi][ni] = __builtin_amdgcn_mfma_f32_16x16x32_bf16(
                        af[mi], bfr[ni], acc[mi][ni], 0, 0, 0);
        }
    }

    const bool isV = (!isQ) && (n0 >= 512);
    if (!isV) {
        bf16* out = isQ ? Qp : Kp;
        const float* bias = isQ ? bq : bk;
        const float qscale = isQ ? 1.8033688f : 1.0f;   // SC folded into Qp
        for (int ni = 0; ni < 2; ++ni) {
            const int n = n0 + wc * 32 + ni * 16 + l16;
            const float bb = bias[n];
            const int hd = n >> 6, d = n & 63;
            for (int mi = 0; mi < 4; ++mi) {
                for (int r = 0; r < 4; ++r) {
                    const int m = m0 + wr * 64 + mi * 16 + quad * 4 + r;
                    const int b = m >> 10, q = m & 1023;
                    out[((size_t)(b * 8 + hd) * 1024 + q) * 64 + d] =
                        (bf16)((acc[mi][ni][r] + bb) * qscale);
                }
            }
        }
    } else {
        // dump tile (+bias) to LDS as Tb[n][m] (n local 0..63, 16 KB) with
        // chunk-XOR swizzle, then store coalesced rows of Vpt [b,h,d,1024]
        __syncthreads();
        for (int ni = 0; ni < 2; ++ni) {
            const int n = wc * 32 + ni * 16 + l16;           // local n 0..63
            const float bb = bv[n0 + n - 512];
            for (int mi = 0; mi < 4; ++mi) {
                const int mb = wr * 64 + mi * 16 + quad * 4;  // local m base (r=0..3)
                const int slot = ((mb >> 3) ^ (n & 15));
                bf16x4 pk = {(bf16)(acc[mi][ni][0] + bb), (bf16)(acc[mi][ni][1] + bb),
                             (bf16)(acc[mi][ni][2] + bb), (bf16)(acc[mi][ni][3] + bb)};
                *(bf16x4*)(sh + n * 128 + slot * 8 + (mb & 7)) = pk;
            }
        }
        __syncthreads();
        const int n = t >> 2, hf = t & 3;                     // 4 threads/row
        const int nv = n0 + n - 512, hd = nv >> 6, d = nv & 63;
        const int b = m0 >> 10, qb = m0 & 1023;
        bf16* dst = Vpt + ((size_t)(b * 8 + hd) * 64 + d) * 1024 + qb;
        #pragma unroll
        for (int j = 0; j < 4; ++j) {
            const int ch = hf * 4 + j;                        // 16 chunks of 8 m
            const int slot = ch ^ (n & 15);
            bf16x8 v8 = *(const bf16x8*)(sh + n * 128 + slot * 8);
            *(bf16x8*)(dst + ch * 8) = v8;
        }
    }
}

// ---------------------------------------------------------------------------
// attn: flash attention per (b,h). 1024 blocks x 4 waves, 64 q/block.
// SPLIT-KEY: wave w owns keys [w*16, w*16+16) of each 64-key tile, ALL 64 q.
// QK^T: S^T = K Q^T via 16x16x32 (A = K rows = wave's keys, B = Q in regs).
// S^T C-layout (row=key quad*4+r, col=q l16) IS the 16x16x16 B-frag layout
// -> P feeds PV (O^T = V^T P^T) entirely in-register: no P LDS round-trip.
// Per wave/kt LDS: 2 b128 (K) + 4 b64 (V) = 5x less than q-split.
// EPILOGUE (rule #20 fix vs prior rev): cross-wave reduce in TWO 32-d halves
// through LDS with COMPILE-TIME register indices only (runtime LDS addresses
// are fine; runtime register-array indices spill everything to scratch —
// prior rev: VGPR 52, FETCH 556 MB, 337 us).
// Q pre-scaled in proj -> P = exp2(S). Mask: ballot fast path.
// ---------------------------------------------------------------------------
__global__ __launch_bounds__(256, 3) void attn_kernel(
    const bf16* __restrict__ Qp, const bf16* __restrict__ Kp,
    const bf16* __restrict__ Vpt, const int* __restrict__ mask,
    bf16* __restrict__ Oa)
{
    const int bh = blockIdx.x & 63, qblk = blockIdx.x >> 6;  // qblk 0..15
    const int b = bh >> 3, hd = bh & 7;
    const int t = threadIdx.x;
    const int wave = t >> 6, lane = t & 63, quad = lane >> 4, l16 = lane & 15;

    // KV: K dbuf (2x8KB) | V dbuf (2x8KB) = 32 KB; reused post-loop as
    // fp32 reduction scratch: scr[w][d_half 0..31][q 0..63] = 32 KB.
    __shared__ __attribute__((aligned(16))) bf16 KV[16384];
    __shared__ float Ls[4][64];

    const bf16* Qbase = Qp + ((size_t)bh * NQ + qblk * 64) * DH;
    const bf16* Kbase = Kp + (size_t)bh * NK * DH;
    const bf16* Vbase = Vpt + (size_t)bh * DH * NK;
    const int* mrow = mask + b * NK;

    // Q B-frags: ALL 64 q of the block (qg = q>>4), full d (hh halves)
    bf16x8 qf[4][2];
    #pragma unroll
    for (int qg = 0; qg < 4; ++qg)
        #pragma unroll
        for (int hh = 0; hh < 2; ++hh)
            qf[qg][hh] = *(const bf16x8*)(Qbase + (size_t)(qg * 16 + l16) * DH + hh * 32 + quad * 8);

    // O^T acc: o[dsub][qg] -> O^T[d = dsub*16 + quad*4 + r][q = qg*16 + l16]
    floatx4 o[4][4];
    float lsum[4] = {0.f, 0.f, 0.f, 0.f};
    #pragma unroll
    for (int i = 0; i < 4; ++i)
        #pragma unroll
        for (int j = 0; j < 4; ++j) o[i][j] = (floatx4){0.f, 0.f, 0.f, 0.f};

    const int r1 = t >> 3, s1 = t & 7;
    const int p1 = s1 ^ (r1 & 7);          // (r1+32)&7 == r1&7
    const bf16* kSrc = Kbase + r1 * 64 + p1 * 8;            // + kt*4096
    const bf16* vSrc = Vbase + (size_t)r1 * 1024 + p1 * 8;  // + kt*64

    // prologue: issue tile 0 into buf 0  (K at KV+0, V at KV+8192)
    async16(kSrc, KV + t * 8);
    async16(kSrc + 32 * 64, KV + (t + 256) * 8);
    async16(vSrc, KV + 8192 + t * 8);
    async16(vSrc + (size_t)32 * 1024, KV + 8192 + (t + 256) * 8);

    const int rowk = wave * 16 + l16;      // this wave's key row in the tile
    for (int kt = 0; kt < NK / 64; ++kt) {
        __syncthreads();   // tile kt loads complete; all waves done with other buf
        const int cur = kt & 1;
        bf16* Ktc = KV + cur * 4096;
        bf16* Vtc = KV + 8192 + cur * 4096;
        if (kt < NK / 64 - 1) {
            const int nxt = 1 - cur;
            async16(kSrc + (kt + 1) * 4096, KV + nxt * 4096 + t * 8);
            async16(kSrc + (kt + 1) * 4096 + 32 * 64, KV + nxt * 4096 + (t + 256) * 8);
            async16(vSrc + (kt + 1) * 64, KV + 8192 + nxt * 4096 + t * 8);
            async16(vSrc + (kt + 1) * 64 + (size_t)32 * 1024, KV + 8192 + nxt * 4096 + (t + 256) * 8);
        }

        // K A-frags: only this wave's 16 key rows (2 b128, conflict-free)
        bf16x8 kb0 = *(const bf16x8*)(Ktc + rowk * 64 + ((quad ^ (rowk & 7)) << 3));
        bf16x8 kb1 = *(const bf16x8*)(Ktc + rowk * 64 + (((quad + 4) ^ (rowk & 7)) << 3));

        // S^T = K Q^T: C col = q (l16), row = key quad*4+r (wave's keys)
        floatx4 sf[4];
        __builtin_amdgcn_s_setprio(1);
        #pragma unroll
        for (int qg = 0; qg < 4; ++qg) {
            floatx4 s = {0.f, 0.f, 0.f, 0.f};
            s = __builtin_amdgcn_mfma_f32_16x16x32_bf16(kb0, qf[qg][0], s, 0, 0, 0);
            s = __builtin_amdgcn_mfma_f32_16x16x32_bf16(kb1, qf[qg][1], s, 0, 0, 0);
            sf[qg] = s;
        }
        __builtin_amdgcn_s_setprio(0);

        // mask: wave-uniform fast path (1 dword/lane + ballot per 64-key tile)
        const int mv = mrow[kt * 64 + lane];
        if (!__all(mv != 0)) {
            const int4 m4 = *(const int4*)&mrow[kt * 64 + wave * 16 + quad * 4];
            #pragma unroll
            for (int qg = 0; qg < 4; ++qg) {
                if (!m4.x) sf[qg][0] = -3.0e38f;
                if (!m4.y) sf[qg][1] = -3.0e38f;
                if (!m4.z) sf[qg][2] = -3.0e38f;
                if (!m4.w) sf[qg][3] = -3.0e38f;
            }
        }
        // P = exp2(S) (scale pre-folded into Qp); VALU row-sum; pack to B-frag
        bf16x4 pb[4];
        #pragma unroll
        for (int qg = 0; qg < 4; ++qg) {
            const float e0 = __builtin_amdgcn_exp2f(sf[qg][0]);
            const float e1 = __builtin_amdgcn_exp2f(sf[qg][1]);
            const float e2 = __builtin_amdgcn_exp2f(sf[qg][2]);
            const float e3 = __builtin_amdgcn_exp2f(sf[qg][3]);
            lsum[qg] += (e0 + e1) + (e2 + e3);
            pb[qg] = (bf16x4){(bf16)e0, (bf16)e1, (bf16)e2, (bf16)e3};
        }
        // PV: O^T[d][q] += V^T[d][wave's 16 keys] * P^T  (x16, P in-register)
        __builtin_amdgcn_s_setprio(1);
        #pragma unroll
        for (int dsub = 0; dsub < 4; ++dsub) {
            const int d = dsub * 16 + l16;
            bf16x4 av = *(const bf16x4*)(Vtc + d * 64 +
                                         (((wave * 4 + quad) ^ ((d & 7) << 1)) << 2));
            #pragma unroll
            for (int qg = 0; qg < 4; ++qg)
                o[dsub][qg] = mfma_16x16x16(av, pb[qg], o[dsub][qg]);
        }
        __builtin_amdgcn_s_setprio(0);
    }

    // ---- epilogue: denominator + cross-wave O^T reduce, 2 halves of 32 d ----
    // lsum reduce (q = qg*16+l16 owned per lane; quad groups hold partials)
    #pragma unroll
    for (int qg = 0; qg < 4; ++qg) {
        lsum[qg] += __shfl_xor(lsum[qg], 16, 64);
        lsum[qg] += __shfl_xor(lsum[qg], 32, 64);
    }
    if (quad == 0)
        #pragma unroll
        for (int qg = 0; qg < 4; ++qg) Ls[wave][qg * 16 + l16] = lsum[qg];

    float* scr = (float*)KV;               // [w][d_half 0..31][q 0..63]
    const int qo = t >> 2, dg = t & 3;     // read-phase ownership
    const size_t orow = ((size_t)(b * NQ + qblk * 64 + qo)) * DIM + hd * 64;
    float invq = 0.f;

    #pragma unroll
    for (int h = 0; h < 2; ++h) {
        __syncthreads();                   // KV/scr free (prev half read done)
        // write own partials for global dsubs 2h, 2h+1 (compile-time indices)
        #pragma unroll
        for (int ds = 0; ds < 2; ++ds) {
            #pragma unroll
            for (int qg = 0; qg < 4; ++qg) {
                float* bp = scr + wave * 2048 + (ds * 16 + quad * 4) * 64 + qg * 16 + l16;
                bp[0]   = o[h * 2 + ds][qg][0];
                bp[64]  = o[h * 2 + ds][qg][1];
                bp[128] = o[h * 2 + ds][qg][2];
                bp[192] = o[h * 2 + ds][qg][3];
            }
        }
        __syncthreads();
        if (h == 0) invq = 1.f / (Ls[0][qo] + Ls[1][qo] + Ls[2][qo] + Ls[3][qo]);
        // read 4-wave partials for (qo, d = h*32 + dg*8 + j), sum, normalize
        bf16x8 pk;
        #pragma unroll
        for (int j = 0; j < 8; ++j) {
            const int dh2 = (dg * 8 + j) * 64 + qo;
            const float s = scr[dh2] + scr[2048 + dh2] + scr[4096 + dh2] + scr[6144 + dh2];
            pk[j] = (bf16)(s * invq);
        }
        *(bf16x8*)(Oa + orow + h * 32 + dg * 8) = pk;
    }
}

// ---------------------------------------------------------------------------
// ffn_gemm: 128x64 tiles (M=128, N=64), BK=64, XOR-swizzled staging,
// m-minor mapping, K-loop double-buffer. Grid 512, LDS 48 KB.
// Yb (bf16) = Oa + relu(Oa @ Wo^T + bo).
// ---------------------------------------------------------------------------
__global__ __launch_bounds__(256) void ffn_gemm(
    const bf16* __restrict__ Oa, const bf16* __restrict__ W,
    const float* __restrict__ bias, bf16* __restrict__ Yb)
{
    __shared__ __attribute__((aligned(16))) bf16 sh[24576];  // 48 KB: A0|A1|B0|B1
    const int t = threadIdx.x;
    const int wave = t >> 6, lane = t & 63, quad = lane >> 4, l16 = lane & 15;
    const int wr = wave >> 1, wc = wave & 1;
    const int m0 = (blockIdx.x & 63) * 128, n0 = (blockIdx.x >> 6) * 64;

    const int r1 = t >> 3, s1 = t & 7;
    const int p1 = s1 ^ (r1 & 7);
    const bf16* aSrc = Oa + (size_t)(m0 + r1) * DIM + p1 * 8;
    const bf16* wSrc = W  + (size_t)(n0 + r1) * DIM + p1 * 8;

    floatx4 acc[4][2];
    for (int i = 0; i < 4; ++i)
        for (int j = 0; j < 2; ++j) acc[i][j] = (floatx4){0.f, 0.f, 0.f, 0.f};

    #pragma unroll
    for (int j = 0; j < 4; ++j)
        async16(aSrc + (size_t)j * 32 * DIM, sh + (t + j * 256) * 8);
    #pragma unroll
    for (int j = 0; j < 2; ++j)
        async16(wSrc + (size_t)j * 32 * DIM, sh + 16384 + (t + j * 256) * 8);

    for (int kt = 0; kt < 8; ++kt) {
        __syncthreads();
        const int cur = kt & 1;
        bf16* Acur = sh + cur * 8192;
        bf16* Bcur = sh + 16384 + cur * 4096;
        if (kt < 7) {
            bf16* Anxt = sh + (1 - cur) * 8192;
            bf16* Bnxt = sh + 16384 + (1 - cur) * 4096;
            const int ko = (kt + 1) * 64;
            #pragma unroll
            for (int j = 0; j < 4; ++j)
                async16(aSrc + ko + (size_t)j * 32 * DIM, Anxt + (t + j * 256) * 8);
            #pragma unroll
            for (int j = 0; j < 2; ++j)
                async16(wSrc + ko + (size_t)j * 32 * DIM, Bnxt + (t + j * 256) * 8);
        }
        #pragma unroll
        for (int ks = 0; ks < 2; ++ks) {
            bf16x8 af[4], bfr[2];
            #pragma unroll
            for (int mi = 0; mi < 4; ++mi) {
                const int row = wr * 64 + mi * 16 + l16;
                af[mi] = *(const bf16x8*)(Acur + row * 64 + (((ks * 4 + quad) ^ (row & 7)) << 3));
            }
            #pragma unroll
            for (int ni = 0; ni < 2; ++ni) {
                const int row = wc * 32 + ni * 16 + l16;
                bfr[ni] = *(const bf16x8*)(Bcur + row * 64 + (((ks * 4 + quad) ^ (row & 7)) << 3));
            }
            #pragma unroll
            for (int mi = 0; mi < 4; ++mi)
                #pragma unroll
                for (int ni = 0; ni < 2; ++ni)
                    acc[mi][ni] = __builtin_amdgcn_mfma_f32_16x16x32_bf16(
                        af[mi], bfr[ni], acc[mi][ni], 0, 0, 0);
        }
    }

    for (int ni = 0; ni < 2; ++ni) {
        const int n = n0 + wc * 32 + ni * 16 + l16;
        const float bb = bias[n];
        for (int mi = 0; mi < 4; ++mi) {
            for (int r = 0; r < 4; ++r) {
                const int m = m0 + wr * 64 + mi * 16 + quad * 4 + r;
                const float ov = (float)Oa[(size_t)m * DIM + n];
                Yb[(size_t)m * DIM + n] = (bf16)(ov + fmaxf(acc[mi][ni][r] + bb, 0.f));
            }
        }
    }
}

// ---------------------------------------------------------------------------
// ln: LayerNorm over last dim (512). One wave per row; bf16 in, fp32 out.
// ---------------------------------------------------------------------------
__global__ __launch_bounds__(256) void ln_kernel(
    const bf16* __restrict__ Y, const float* __restrict__ gamma,
    const float* __restrict__ beta, float* __restrict__ out)
{
    const int row  = blockIdx.x * 4 + (threadIdx.x >> 6);
    const int lane = threadIdx.x & 63;
    bf16x8 v = *(const bf16x8*)(Y + (size_t)row * DIM + lane * 8);
    float f[8];
    float s = 0.f, sq = 0.f;
    #pragma unroll
    for (int j = 0; j < 8; ++j) {
        f[j] = (float)v[j];
        s += f[j];
        sq += f[j] * f[j];
    }
    for (int mk = 32; mk >= 1; mk >>= 1) {
        s  += __shfl_xor(s,  mk, 64);
        sq += __shfl_xor(sq, mk, 64);
    }
    const float mu  = s * (1.f / 512.f);
    const float var = sq * (1.f / 512.f) - mu * mu;
    const float inv = rsqrtf(var + 1e-5f);
    float4 g1 = ((const float4*)gamma)[lane * 2];
    float4 g2 = ((const float4*)gamma)[lane * 2 + 1];
    float4 b1 = ((const float4*)beta)[lane * 2];
    float4 b2 = ((const float4*)beta)[lane * 2 + 1];
    float4 o1, o2;
    o1.x = (f[0] - mu) * inv * g1.x + b1.x;
    o1.y = (f[1] - mu) * inv * g1.y + b1.y;
    o1.z = (f[2] - mu) * inv * g1.z + b1.z;
    o1.w = (f[3] - mu) * inv * g1.w + b1.w;
    o2.x = (f[4] - mu) * inv * g2.x + b2.x;
    o2.y = (f[5] - mu) * inv * g2.y + b2.y;
    o2.z = (f[6] - mu) * inv * g2.z + b2.z;
    o2.w = (f[7] - mu) * inv * g2.w + b2.w;
    float* orow = out + (size_t)row * DIM;
    ((float4*)orow)[lane * 2]     = o1;
    ((float4*)orow)[lane * 2 + 1] = o2;
}

// ---------------------------------------------------------------------------
extern "C" void kernel_launch(void* const* d_in, const int* in_sizes, int n_in,
                              void* d_out, int out_size, void* d_ws, size_t ws_size,
                              hipStream_t stream) {
    const float* Q  = (const float*)d_in[0];
    const float* K  = (const float*)d_in[1];
    const int*   mask = (const int*)d_in[2];
    const float* Wq = (const float*)d_in[3];
    const float* bq = (const float*)d_in[4];
    const float* Wk = (const float*)d_in[5];
    const float* bk = (const float*)d_in[6];
    const float* Wv = (const float*)d_in[7];
    const float* bv = (const float*)d_in[8];
    const float* Wo = (const float*)d_in[9];
    const float* bo = (const float*)d_in[10];
    const float* gamma = (const float*)d_in[11];
    const float* beta  = (const float*)d_in[12];

    char* ws = (char*)d_ws;
    bf16* Wt  = (bf16*)(ws);                   // 2 MB (4 x 512x512 bf16, transposed)
    bf16* Qb  = (bf16*)(ws + 2097152);         // 8 MB
    bf16* Kb  = (bf16*)(ws + 10485760);        // 8 MB
    bf16* Qp  = (bf16*)(ws + 18874368);        // 8 MB  [b,h,q,64] (pre-scaled)
    bf16* Kp  = (bf16*)(ws + 27262976);        // 8 MB  [b,h,k,64]
    bf16* Vpt = (bf16*)(ws + 35651584);        // 8 MB  [b,h,d,1024]
    bf16* Oa  = (bf16*)(ws + 44040192);        // 8 MB  [b,q,512]
    bf16* Yb  = (bf16*)(ws + 52428800);        // 8 MB  [b,q,512] bf16
    float* out = (float*)d_out;

    prep_fused<<<4352, 256, 0, stream>>>(Q, K, Wq, Wk, Wv, Wo, Qb, Kb, Wt);
    proj_fused<<<1536, 256, 0, stream>>>(Qb, Kb, Wt, bq, bk, bv, Qp, Kp, Vpt);
    attn_kernel<<<1024, 256, 0, stream>>>(Qp, Kp, Vpt, mask, Oa);
    ffn_gemm<<<512, 256, 0, stream>>>(Oa, Wt + 3 * 262144, bo, Yb);
    ln_kernel<<<2048, 256, 0, stream>>>(Yb, gamma, beta, out);
}

// Round 7
// 170.526 us; speedup vs baseline: 2.7070x; 1.0214x over previous
//
#include <hip/hip_runtime.h>

typedef __bf16 bf16;
typedef bf16 bf16x4 __attribute__((ext_vector_type(4)));
typedef bf16 bf16x8 __attribute__((ext_vector_type(8)));
typedef float floatx4 __attribute__((ext_vector_type(4)));
typedef short short4i __attribute__((ext_vector_type(4)));

#define NB 8
#define NQ 1024
#define NK 1024
#define DIM 512
#define NH 8
#define DH 64

// async global->LDS, 16B per lane. LDS dest must be wave-uniform base + lane*16B.
__device__ __forceinline__ void async16(const void* g, void* l) {
    __builtin_amdgcn_global_load_lds(
        (const __attribute__((address_space(1))) unsigned int*)(unsigned long long)(g),
        (__attribute__((address_space(3))) unsigned int*)(unsigned long long)(l),
        16, 0, 0);
}

// 16x16x16 bf16 MFMA (K=16). B-frag layout B[k=quad*4+j][col=l16] equals the
// S^T C-layout (row=quad*4+r, col=l16) -> P feeds PV in-register, no LDS
// round-trip. (Layout HW-verified: rounds 5/6 passed numerics using this.)
__device__ __forceinline__ floatx4 mfma_16x16x16(bf16x4 a, bf16x4 b, floatx4 c) {
#if __has_builtin(__builtin_amdgcn_mfma_f32_16x16x16_bf16)
    return __builtin_amdgcn_mfma_f32_16x16x16_bf16(a, b, c, 0, 0, 0);
#elif __has_builtin(__builtin_amdgcn_mfma_f32_16x16x16bf16_1k)
    return __builtin_amdgcn_mfma_f32_16x16x16bf16_1k(
        __builtin_bit_cast(short4i, a), __builtin_bit_cast(short4i, b), c, 0, 0, 0);
#else
    asm volatile("v_mfma_f32_16x16x16_bf16 %0, %1, %2, %0\n\ts_nop 7\n\ts_nop 7"
                 : "+v"(c) : "v"(a), "v"(b));
    return c;
#endif
}

// ---------------------------------------------------------------------------
// prep_fused: blocks [0,4096): cast Q,K fp32->bf16 (float4 vectorized);
//             blocks [4096,4352): Wt[w][n][k] = (bf16)W[k][n], LDS 64x64 tiles.
// ---------------------------------------------------------------------------
__global__ __launch_bounds__(256) void prep_fused(
    const float* __restrict__ Q, const float* __restrict__ K,
    const float* __restrict__ Wq, const float* __restrict__ Wk,
    const float* __restrict__ Wv, const float* __restrict__ Wo,
    bf16* __restrict__ Qb, bf16* __restrict__ Kb, bf16* __restrict__ Wt)
{
    __shared__ bf16 Tl[64][68];
    const int bid = blockIdx.x;
    if (bid < 4096) {
        const int i = bid * 256 + threadIdx.x;   // float4 index
        float4 a = ((const float4*)Q)[i];
        float4 c = ((const float4*)K)[i];
        bf16x4 qa = {(bf16)a.x, (bf16)a.y, (bf16)a.z, (bf16)a.w};
        bf16x4 ka = {(bf16)c.x, (bf16)c.y, (bf16)c.z, (bf16)c.w};
        *(bf16x4*)(Qb + (size_t)i * 4) = qa;
        *(bf16x4*)(Kb + (size_t)i * 4) = ka;
    } else {
        const int bid2 = bid - 4096;
        const int w = bid2 >> 6;
        const int bx = bid2 & 7, by = (bid2 >> 3) & 7;
        const float* W = (w == 0) ? Wq : (w == 1) ? Wk : (w == 2) ? Wv : Wo;
        bf16* out = Wt + (size_t)w * DIM * DIM;
        const int k0 = bx * 64, n0 = by * 64;
        const int tx = threadIdx.x & 15, ty = threadIdx.x >> 4;
        for (int pass = 0; pass < 4; ++pass) {
            int k = ty + pass * 16;
            float4 v = *(const float4*)&W[(size_t)(k0 + k) * DIM + n0 + tx * 4];
            Tl[tx * 4 + 0][k] = (bf16)v.x;
            Tl[tx * 4 + 1][k] = (bf16)v.y;
            Tl[tx * 4 + 2][k] = (bf16)v.z;
            Tl[tx * 4 + 3][k] = (bf16)v.w;
        }
        __syncthreads();
        for (int pass = 0; pass < 4; ++pass) {
            int n = ty + pass * 16;
            bf16x4 ov = *(const bf16x4*)&Tl[n][tx * 4];
            *(bf16x4*)&out[(size_t)(n0 + n) * DIM + k0 + tx * 4] = ov;
        }
    }
}

// ---------------------------------------------------------------------------
// proj_fused: 128x64 tiles (M=128, N=64), BK=64, XOR-swizzled async staging,
// m-minor block mapping. LDS 48 KB -> 3 blocks/CU. Grid 1536 = 6/CU in two
// full rounds, 3 waves/SIMD. Wave grid 2x2, wave tile 64x32, acc[4][2].
// blocks [0,512):    Q proj -> Qp head layout [b,h,q,64], PRE-SCALED by
//                    SC = 1/(sqrt(64)*0.1)*log2(e) so attn S is exp2-ready.
// blocks [512,1536): KV proj: n<512 -> Kp head layout; n>=512 -> Vpt
//                    [b,h,d,1024] via in-LDS transpose (coalesced stores).
// ---------------------------------------------------------------------------
__global__ __launch_bounds__(256) void proj_fused(
    const bf16* __restrict__ Qb, const bf16* __restrict__ Kb,
    const bf16* __restrict__ Wt,
    const float* __restrict__ bq, const float* __restrict__ bk,
    const float* __restrict__ bv,
    bf16* __restrict__ Qp, bf16* __restrict__ Kp, bf16* __restrict__ Vpt)
{
    // 48 KB: A0(16K) | A1(16K) | B0(8K) | B1(8K)   (bf16 units: 8192|8192|4096|4096)
    __shared__ __attribute__((aligned(16))) bf16 sh[24576];
    const int t = threadIdx.x;
    const int wave = t >> 6, lane = t & 63, quad = lane >> 4, l16 = lane & 15;
    const int wr = wave >> 1, wc = wave & 1;
    const int bid = blockIdx.x;
    const bool isQ = bid < 512;
    const bf16* A; const bf16* W; int m0, n0;
    if (isQ) { A = Qb; W = Wt;             m0 = (bid & 63) * 128;  n0 = (bid >> 6) * 64; }
    else     { int b2 = bid - 512;
               A = Kb; W = Wt + 512 * DIM; m0 = (b2 & 63) * 128;   n0 = (b2 >> 6) * 64; }

    const int r1 = t >> 3, s1 = t & 7;
    const int p1 = s1 ^ (r1 & 7);          // rows r1+32j keep row&7
    const bf16* aSrc = A + (size_t)(m0 + r1) * DIM + p1 * 8;
    const bf16* wSrc = W + (size_t)(n0 + r1) * DIM + p1 * 8;

    floatx4 acc[4][2];
    for (int i = 0; i < 4; ++i)
        for (int j = 0; j < 2; ++j) acc[i][j] = (floatx4){0.f, 0.f, 0.f, 0.f};

    // prologue: issue kt=0 into buf 0
    #pragma unroll
    for (int j = 0; j < 4; ++j)
        async16(aSrc + (size_t)j * 32 * DIM, sh + (t + j * 256) * 8);
    #pragma unroll
    for (int j = 0; j < 2; ++j)
        async16(wSrc + (size_t)j * 32 * DIM, sh + 16384 + (t + j * 256) * 8);

    for (int kt = 0; kt < 8; ++kt) {
        __syncthreads();   // tile kt loads done; all waves done with other buf
        const int cur = kt & 1;
        bf16* Acur = sh + cur * 8192;
        bf16* Bcur = sh + 16384 + cur * 4096;
        if (kt < 7) {
            bf16* Anxt = sh + (1 - cur) * 8192;
            bf16* Bnxt = sh + 16384 + (1 - cur) * 4096;
            const int ko = (kt + 1) * 64;
            #pragma unroll
            for (int j = 0; j < 4; ++j)
                async16(aSrc + ko + (size_t)j * 32 * DIM, Anxt + (t + j * 256) * 8);
            #pragma unroll
            for (int j = 0; j < 2; ++j)
                async16(wSrc + ko + (size_t)j * 32 * DIM, Bnxt + (t + j * 256) * 8);
        }
        #pragma unroll
        for (int ks = 0; ks < 2; ++ks) {
            bf16x8 af[4], bfr[2];
            #pragma unroll
            for (int mi = 0; mi < 4; ++mi) {
                const int row = wr * 64 + mi * 16 + l16;
                af[mi] = *(const bf16x8*)(Acur + row * 64 + (((ks * 4 + quad) ^ (row & 7)) << 3));
            }
            #pragma unroll
            for (int ni = 0; ni < 2; ++ni) {
                const int row = wc * 32 + ni * 16 + l16;
                bfr[ni] = *(const bf16x8*)(Bcur + row * 64 + (((ks * 4 + quad) ^ (row & 7)) << 3));
            }
            #pragma unroll
            for (int mi = 0; mi < 4; ++mi)
                #pragma unroll
                for (int ni = 0; ni < 2; ++ni)
                    acc[mi][ni] = __builtin_amdgcn_mfma_f32_16x16x32_bf16(
                        af[mi], bfr[ni], acc[mi][ni], 0, 0, 0);
        }
    }

    const bool isV = (!isQ) && (n0 >= 512);
    if (!isV) {
        bf16* out = isQ ? Qp : Kp;
        const float* bias = isQ ? bq : bk;
        const float qscale = isQ ? 1.8033688f : 1.0f;   // SC folded into Qp
        for (int ni = 0; ni < 2; ++ni) {
            const int n = n0 + wc * 32 + ni * 16 + l16;
            const float bb = bias[n];
            const int hd = n >> 6, d = n & 63;
            for (int mi = 0; mi < 4; ++mi) {
                for (int r = 0; r < 4; ++r) {
                    const int m = m0 + wr * 64 + mi * 16 + quad * 4 + r;
                    const int b = m >> 10, q = m & 1023;
                    out[((size_t)(b * 8 + hd) * 1024 + q) * 64 + d] =
                        (bf16)((acc[mi][ni][r] + bb) * qscale);
                }
            }
        }
    } else {
        // dump tile (+bias) to LDS as Tb[n][m] (n local 0..63, 16 KB) with
        // chunk-XOR swizzle, then store coalesced rows of Vpt [b,h,d,1024]
        __syncthreads();
        for (int ni = 0; ni < 2; ++ni) {
            const int n = wc * 32 + ni * 16 + l16;           // local n 0..63
            const float bb = bv[n0 + n - 512];
            for (int mi = 0; mi < 4; ++mi) {
                const int mb = wr * 64 + mi * 16 + quad * 4;  // local m base (r=0..3)
                const int slot = ((mb >> 3) ^ (n & 15));
                bf16x4 pk = {(bf16)(acc[mi][ni][0] + bb), (bf16)(acc[mi][ni][1] + bb),
                             (bf16)(acc[mi][ni][2] + bb), (bf16)(acc[mi][ni][3] + bb)};
                *(bf16x4*)(sh + n * 128 + slot * 8 + (mb & 7)) = pk;
            }
        }
        __syncthreads();
        const int n = t >> 2, hf = t & 3;                     // 4 threads/row
        const int nv = n0 + n - 512, hd = nv >> 6, d = nv & 63;
        const int b = m0 >> 10, qb = m0 & 1023;
        bf16* dst = Vpt + ((size_t)(b * 8 + hd) * 64 + d) * 1024 + qb;
        #pragma unroll
        for (int j = 0; j < 4; ++j) {
            const int ch = hf * 4 + j;                        // 16 chunks of 8 m
            const int slot = ch ^ (n & 15);
            bf16x8 v8 = *(const bf16x8*)(sh + n * 128 + slot * 8);
            *(bf16x8*)(dst + ch * 8) = v8;
        }
    }
}

// ---------------------------------------------------------------------------
// attn: flash attention per (b,h). 1024 blocks x 4 waves, 64 q/block,
// 16 q/wave (round-4 q-split structure: conflict-free quad-spread K reads,
// 4 blocks/CU at 40 KB LDS) + IN-REGISTER P (round-5/6 verified x16 layout):
// S^T = K Q^T (x32) leaves P^T[key=quad*4+r][q=l16] in regs, which IS the
// x16 B-frag -> PV = O^T = V^T P^T via 16 x16 MFMAs, NO P LDS round-trip.
// Deletes Pl (8 b64 w + 2 b128 r + ~1M conflict cy/dispatch) and osum MFMAs
// (denominator is lane-local VALU now: lane owns one q row).
// Epilogue: normalize in-reg, transpose via 8 KB LDS tile (2-way-free XOR
// swizzle, compile-time reg indices only), coalesced bf16x8 stores.
// Q pre-scaled in proj -> P = exp2(S). Mask: ballot fast path.
// ---------------------------------------------------------------------------
__global__ __launch_bounds__(256) void attn_kernel(
    const bf16* __restrict__ Qp, const bf16* __restrict__ Kp,
    const bf16* __restrict__ Vpt, const int* __restrict__ mask,
    bf16* __restrict__ Oa)
{
    const int bh = blockIdx.x & 63, qblk = blockIdx.x >> 6;  // qblk 0..15
    const int b = bh >> 3, hd = bh & 7;
    const int t = threadIdx.x;
    const int wave = t >> 6, lane = t & 63, quad = lane >> 4, l16 = lane & 15;

    __shared__ __attribute__((aligned(16))) bf16 Kt[2][64 * 64];
    __shared__ __attribute__((aligned(16))) bf16 Vt[2][64 * 64];
    __shared__ __attribute__((aligned(16))) bf16 Ot[64 * 64];   // O transpose buf

    const bf16* Qbase = Qp + ((size_t)bh * NQ + qblk * 64 + wave * 16) * DH;
    const bf16* Kbase = Kp + (size_t)bh * NK * DH;
    const bf16* Vbase = Vpt + (size_t)bh * DH * NK;
    const int* mrow = mask + b * NK;

    // Q B-frags (col=q=l16, k = hh*32 + quad*8 + j), kept in regs
    bf16x8 qf[2];
    #pragma unroll
    for (int hh = 0; hh < 2; ++hh)
        qf[hh] = *(const bf16x8*)(Qbase + (size_t)l16 * DH + hh * 32 + quad * 8);

    // O acc: o[dg][r] = O[q = wave*16 + l16][d = dg*16 + quad*4 + r]
    floatx4 o[4];
    float lsum = 0.f;
    #pragma unroll
    for (int i = 0; i < 4; ++i) o[i] = (floatx4){0.f, 0.f, 0.f, 0.f};

    const int r1 = t >> 3, s1 = t & 7;
    const int p1 = s1 ^ (r1 & 7);          // (r1+32)&7 == r1&7
    const bf16* kSrc = Kbase + r1 * 64 + p1 * 8;            // + kt*4096
    const bf16* vSrc = Vbase + (size_t)r1 * 1024 + p1 * 8;  // + kt*64

    // prologue: issue tile 0 into buf 0
    async16(kSrc, Kt[0] + t * 8);
    async16(kSrc + 32 * 64, Kt[0] + (t + 256) * 8);
    async16(vSrc, Vt[0] + t * 8);
    async16(vSrc + (size_t)32 * 1024, Vt[0] + (t + 256) * 8);

    for (int kt = 0; kt < NK / 64; ++kt) {
        __syncthreads();   // tile kt loads complete; all waves done with other buf
        const int cur = kt & 1;
        if (kt < NK / 64 - 1) {
            const int nxt = 1 - cur;
            async16(kSrc + (kt + 1) * 4096, Kt[nxt] + t * 8);
            async16(kSrc + (kt + 1) * 4096 + 32 * 64, Kt[nxt] + (t + 256) * 8);
            async16(vSrc + (kt + 1) * 64, Vt[nxt] + t * 8);
            async16(vSrc + (kt + 1) * 64 + (size_t)32 * 1024, Vt[nxt] + (t + 256) * 8);
        }

        // K A-frags (lane = key-within-subtile), conflict-free quad-spread
        bf16x8 kb[4][2];
        #pragma unroll
        for (int sub = 0; sub < 4; ++sub) {
            const int rowk = sub * 16 + l16;
            kb[sub][0] = *(const bf16x8*)(Kt[cur] + rowk * 64 + ((quad ^ (rowk & 7)) << 3));
            kb[sub][1] = *(const bf16x8*)(Kt[cur] + rowk * 64 + (((quad + 4) ^ (rowk & 7)) << 3));
        }
        // S^T = K Q^T: C col = q (l16), row = key-within-sub (quad*4+r)
        floatx4 sf[4];
        __builtin_amdgcn_s_setprio(1);
        #pragma unroll
        for (int sub = 0; sub < 4; ++sub) {
            floatx4 s = {0.f, 0.f, 0.f, 0.f};
            s = __builtin_amdgcn_mfma_f32_16x16x32_bf16(kb[sub][0], qf[0], s, 0, 0, 0);
            s = __builtin_amdgcn_mfma_f32_16x16x32_bf16(kb[sub][1], qf[1], s, 0, 0, 0);
            sf[sub] = s;
        }
        __builtin_amdgcn_s_setprio(0);

        // mask: wave-uniform fast path (1 dword/lane + ballot per 64-key tile)
        const int mv = mrow[kt * 64 + lane];
        if (!__all(mv != 0)) {
            #pragma unroll
            for (int sub = 0; sub < 4; ++sub) {
                const int4 m4 = *(const int4*)&mrow[kt * 64 + sub * 16 + quad * 4];
                if (!m4.x) sf[sub][0] = -3.0e38f;
                if (!m4.y) sf[sub][1] = -3.0e38f;
                if (!m4.z) sf[sub][2] = -3.0e38f;
                if (!m4.w) sf[sub][3] = -3.0e38f;
            }
        }
        // P = exp2(S) (scale pre-folded into Qp); lane-local row sum; pack
        bf16x4 pb[4];
        #pragma unroll
        for (int sub = 0; sub < 4; ++sub) {
            const float e0 = __builtin_amdgcn_exp2f(sf[sub][0]);
            const float e1 = __builtin_amdgcn_exp2f(sf[sub][1]);
            const float e2 = __builtin_amdgcn_exp2f(sf[sub][2]);
            const float e3 = __builtin_amdgcn_exp2f(sf[sub][3]);
            lsum += (e0 + e1) + (e2 + e3);
            pb[sub] = (bf16x4){(bf16)e0, (bf16)e1, (bf16)e2, (bf16)e3};
        }
        // PV: O^T = V^T P^T via x16; A = V^T[d = dg*16+l16][16 keys of sub]
        // (b64 reads, 2-way-free banks), B = pb[sub] in-register.
        __builtin_amdgcn_s_setprio(1);
        #pragma unroll
        for (int sub = 0; sub < 4; ++sub) {
            #pragma unroll
            for (int dg = 0; dg < 4; ++dg) {
                const int d = dg * 16 + l16;
                bf16x4 av = *(const bf16x4*)(Vt[cur] + d * 64 +
                    (((sub * 2 + (quad >> 1)) ^ (l16 & 7)) << 3) + (quad & 1) * 4);
                o[dg] = mfma_16x16x16(av, pb[sub], o[dg]);
            }
        }
        __builtin_amdgcn_s_setprio(0);
    }

    // ---- epilogue: lane owns q = wave*16 + l16 entirely ----
    lsum += __shfl_xor(lsum, 16, 64);
    lsum += __shfl_xor(lsum, 32, 64);
    const float inv = 1.f / lsum;

    // normalize + write O[q][d] into LDS tile (XOR chunk swizzle, 2-way free)
    {
        const int q = wave * 16 + l16;
        #pragma unroll
        for (int dg = 0; dg < 4; ++dg) {
            const int ch = dg * 2 + (quad >> 1);             // d chunk = d>>3
            const int slot = ch ^ (l16 & 7);
            bf16x4 pk = {(bf16)(o[dg][0] * inv), (bf16)(o[dg][1] * inv),
                         (bf16)(o[dg][2] * inv), (bf16)(o[dg][3] * inv)};
            *(bf16x4*)(Ot + q * 64 + slot * 8 + (quad & 1) * 4) = pk;
        }
    }
    __syncthreads();
    {   // coalesced store: 4 threads/row, 2 x b128 each
        const int q = t >> 2, cp = t & 3;
        bf16* orow = Oa + ((size_t)(b * NQ + qblk * 64 + q)) * DIM + hd * 64;
        #pragma unroll
        for (int j = 0; j < 2; ++j) {
            const int c = cp * 2 + j;
            bf16x8 v = *(const bf16x8*)(Ot + q * 64 + (c ^ (q & 7)) * 8);
            *(bf16x8*)(orow + c * 8) = v;
        }
    }
}

// ---------------------------------------------------------------------------
// ffn_gemm: 128x64 tiles (M=128, N=64), BK=64, XOR-swizzled staging,
// m-minor mapping, K-loop double-buffer. Grid 512, LDS 48 KB.
// Yb (bf16) = Oa + relu(Oa @ Wo^T + bo).
// ---------------------------------------------------------------------------
__global__ __launch_bounds__(256) void ffn_gemm(
    const bf16* __restrict__ Oa, const bf16* __restrict__ W,
    const float* __restrict__ bias, bf16* __restrict__ Yb)
{
    __shared__ __attribute__((aligned(16))) bf16 sh[24576];  // 48 KB: A0|A1|B0|B1
    const int t = threadIdx.x;
    const int wave = t >> 6, lane = t & 63, quad = lane >> 4, l16 = lane & 15;
    const int wr = wave >> 1, wc = wave & 1;
    const int m0 = (blockIdx.x & 63) * 128, n0 = (blockIdx.x >> 6) * 64;

    const int r1 = t >> 3, s1 = t & 7;
    const int p1 = s1 ^ (r1 & 7);
    const bf16* aSrc = Oa + (size_t)(m0 + r1) * DIM + p1 * 8;
    const bf16* wSrc = W  + (size_t)(n0 + r1) * DIM + p1 * 8;

    floatx4 acc[4][2];
    for (int i = 0; i < 4; ++i)
        for (int j = 0; j < 2; ++j) acc[i][j] = (floatx4){0.f, 0.f, 0.f, 0.f};

    #pragma unroll
    for (int j = 0; j < 4; ++j)
        async16(aSrc + (size_t)j * 32 * DIM, sh + (t + j * 256) * 8);
    #pragma unroll
    for (int j = 0; j < 2; ++j)
        async16(wSrc + (size_t)j * 32 * DIM, sh + 16384 + (t + j * 256) * 8);

    for (int kt = 0; kt < 8; ++kt) {
        __syncthreads();
        const int cur = kt & 1;
        bf16* Acur = sh + cur * 8192;
        bf16* Bcur = sh + 16384 + cur * 4096;
        if (kt < 7) {
            bf16* Anxt = sh + (1 - cur) * 8192;
            bf16* Bnxt = sh + 16384 + (1 - cur) * 4096;
            const int ko = (kt + 1) * 64;
            #pragma unroll
            for (int j = 0; j < 4; ++j)
                async16(aSrc + ko + (size_t)j * 32 * DIM, Anxt + (t + j * 256) * 8);
            #pragma unroll
            for (int j = 0; j < 2; ++j)
                async16(wSrc + ko + (size_t)j * 32 * DIM, Bnxt + (t + j * 256) * 8);
        }
        #pragma unroll
        for (int ks = 0; ks < 2; ++ks) {
            bf16x8 af[4], bfr[2];
            #pragma unroll
            for (int mi = 0; mi < 4; ++mi) {
                const int row = wr * 64 + mi * 16 + l16;
                af[mi] = *(const bf16x8*)(Acur + row * 64 + (((ks * 4 + quad) ^ (row & 7)) << 3));
            }
            #pragma unroll
            for (int ni = 0; ni < 2; ++ni) {
                const int row = wc * 32 + ni * 16 + l16;
                bfr[ni] = *(const bf16x8*)(Bcur + row * 64 + (((ks * 4 + quad) ^ (row & 7)) << 3));
            }
            #pragma unroll
            for (int mi = 0; mi < 4; ++mi)
                #pragma unroll
                for (int ni = 0; ni < 2; ++ni)
                    acc[mi][ni] = __builtin_amdgcn_mfma_f32_16x16x32_bf16(
                        af[mi], bfr[ni], acc[mi][ni], 0, 0, 0);
        }
    }

    for (int ni = 0; ni < 2; ++ni) {
        const int n = n0 + wc * 32 + ni * 16 + l16;
        const float bb = bias[n];
        for (int mi = 0; mi < 4; ++mi) {
            for (int r = 0; r < 4; ++r) {
                const int m = m0 + wr * 64 + mi * 16 + quad * 4 + r;
                const float ov = (float)Oa[(size_t)m * DIM + n];
                Yb[(size_t)m * DIM + n] = (bf16)(ov + fmaxf(acc[mi][ni][r] + bb, 0.f));
            }
        }
    }
}

// ---------------------------------------------------------------------------
// ln: LayerNorm over last dim (512). One wave per row; bf16 in, fp32 out.
// ---------------------------------------------------------------------------
__global__ __launch_bounds__(256) void ln_kernel(
    const bf16* __restrict__ Y, const float* __restrict__ gamma,
    const float* __restrict__ beta, float* __restrict__ out)
{
    const int row  = blockIdx.x * 4 + (threadIdx.x >> 6);
    const int lane = threadIdx.x & 63;
    bf16x8 v = *(const bf16x8*)(Y + (size_t)row * DIM + lane * 8);
    float f[8];
    float s = 0.f, sq = 0.f;
    #pragma unroll
    for (int j = 0; j < 8; ++j) {
        f[j] = (float)v[j];
        s += f[j];
        sq += f[j] * f[j];
    }
    for (int mk = 32; mk >= 1; mk >>= 1) {
        s  += __shfl_xor(s,  mk, 64);
        sq += __shfl_xor(sq, mk, 64);
    }
    const float mu  = s * (1.f / 512.f);
    const float var = sq * (1.f / 512.f) - mu * mu;
    const float inv = rsqrtf(var + 1e-5f);
    float4 g1 = ((const float4*)gamma)[lane * 2];
    float4 g2 = ((const float4*)gamma)[lane * 2 + 1];
    float4 b1 = ((const float4*)beta)[lane * 2];
    float4 b2 = ((const float4*)beta)[lane * 2 + 1];
    float4 o1, o2;
    o1.x = (f[0] - mu) * inv * g1.x + b1.x;
    o1.y = (f[1] - mu) * inv * g1.y + b1.y;
    o1.z = (f[2] - mu) * inv * g1.z + b1.z;
    o1.w = (f[3] - mu) * inv * g1.w + b1.w;
    o2.x = (f[4] - mu) * inv * g2.x + b2.x;
    o2.y = (f[5] - mu) * inv * g2.y + b2.y;
    o2.z = (f[6] - mu) * inv * g2.z + b2.z;
    o2.w = (f[7] - mu) * inv * g2.w + b2.w;
    float* orow = out + (size_t)row * DIM;
    ((float4*)orow)[lane * 2]     = o1;
    ((float4*)orow)[lane * 2 + 1] = o2;
}

// ---------------------------------------------------------------------------
extern "C" void kernel_launch(void* const* d_in, const int* in_sizes, int n_in,
                              void* d_out, int out_size, void* d_ws, size_t ws_size,
                              hipStream_t stream) {
    const float* Q  = (const float*)d_in[0];
    const float* K  = (const float*)d_in[1];
    const int*   mask = (const int*)d_in[2];
    const float* Wq = (const float*)d_in[3];
    const float* bq = (const float*)d_in[4];
    const float* Wk = (const float*)d_in[5];
    const float* bk = (const float*)d_in[6];
    const float* Wv = (const float*)d_in[7];
    const float* bv = (const float*)d_in[8];
    const float* Wo = (const float*)d_in[9];
    const float* bo = (const float*)d_in[10];
    const float* gamma = (const float*)d_in[11];
    const float* beta  = (const float*)d_in[12];

    char* ws = (char*)d_ws;
    bf16* Wt  = (bf16*)(ws);                   // 2 MB (4 x 512x512 bf16, transposed)
    bf16* Qb  = (bf16*)(ws + 2097152);         // 8 MB
    bf16* Kb  = (bf16*)(ws + 10485760);        // 8 MB
    bf16* Qp  = (bf16*)(ws + 18874368);        // 8 MB  [b,h,q,64] (pre-scaled)
    bf16* Kp  = (bf16*)(ws + 27262976);        // 8 MB  [b,h,k,64]
    bf16* Vpt = (bf16*)(ws + 35651584);        // 8 MB  [b,h,d,1024]
    bf16* Oa  = (bf16*)(ws + 44040192);        // 8 MB  [b,q,512]
    bf16* Yb  = (bf16*)(ws + 52428800);        // 8 MB  [b,q,512] bf16
    float* out = (float*)d_out;

    prep_fused<<<4352, 256, 0, stream>>>(Q, K, Wq, Wk, Wv, Wo, Qb, Kb, Wt);
    proj_fused<<<1536, 256, 0, stream>>>(Qb, Kb, Wt, bq, bk, bv, Qp, Kp, Vpt);
    attn_kernel<<<1024, 256, 0, stream>>>(Qp, Kp, Vpt, mask, Oa);
    ffn_gemm<<<512, 256, 0, stream>>>(Oa, Wt + 3 * 262144, bo, Yb);
    ln_kernel<<<2048, 256, 0, stream>>>(Yb, gamma, beta, out);
}

// Round 8
// 165.886 us; speedup vs baseline: 2.7827x; 1.0280x over previous
//
#include <hip/hip_runtime.h>

typedef __bf16 bf16;
typedef bf16 bf16x4 __attribute__((ext_vector_type(4)));
typedef bf16 bf16x8 __attribute__((ext_vector_type(8)));
typedef float floatx4 __attribute__((ext_vector_type(4)));

#define NB 8
#define NQ 1024
#define NK 1024
#define DIM 512
#define NH 8
#define DH 64

// async global->LDS, 16B per lane. LDS dest must be wave-uniform base + lane*16B.
__device__ __forceinline__ void async16(const void* g, void* l) {
    __builtin_amdgcn_global_load_lds(
        (const __attribute__((address_space(1))) unsigned int*)(unsigned long long)(g),
        (__attribute__((address_space(3))) unsigned int*)(unsigned long long)(l),
        16, 0, 0);
}

// ---------------------------------------------------------------------------
// prep_fused: blocks [0,4096): cast Q,K fp32->bf16 (float4 vectorized);
//             blocks [4096,4352): Wt[w][n][k] = (bf16)W[k][n], LDS 64x64 tiles.
// ---------------------------------------------------------------------------
__global__ __launch_bounds__(256) void prep_fused(
    const float* __restrict__ Q, const float* __restrict__ K,
    const float* __restrict__ Wq, const float* __restrict__ Wk,
    const float* __restrict__ Wv, const float* __restrict__ Wo,
    bf16* __restrict__ Qb, bf16* __restrict__ Kb, bf16* __restrict__ Wt)
{
    __shared__ bf16 Tl[64][68];
    const int bid = blockIdx.x;
    if (bid < 4096) {
        const int i = bid * 256 + threadIdx.x;   // float4 index
        float4 a = ((const float4*)Q)[i];
        float4 c = ((const float4*)K)[i];
        bf16x4 qa = {(bf16)a.x, (bf16)a.y, (bf16)a.z, (bf16)a.w};
        bf16x4 ka = {(bf16)c.x, (bf16)c.y, (bf16)c.z, (bf16)c.w};
        *(bf16x4*)(Qb + (size_t)i * 4) = qa;
        *(bf16x4*)(Kb + (size_t)i * 4) = ka;
    } else {
        const int bid2 = bid - 4096;
        const int w = bid2 >> 6;
        const int bx = bid2 & 7, by = (bid2 >> 3) & 7;
        const float* W = (w == 0) ? Wq : (w == 1) ? Wk : (w == 2) ? Wv : Wo;
        bf16* out = Wt + (size_t)w * DIM * DIM;
        const int k0 = bx * 64, n0 = by * 64;
        const int tx = threadIdx.x & 15, ty = threadIdx.x >> 4;
        for (int pass = 0; pass < 4; ++pass) {
            int k = ty + pass * 16;
            float4 v = *(const float4*)&W[(size_t)(k0 + k) * DIM + n0 + tx * 4];
            Tl[tx * 4 + 0][k] = (bf16)v.x;
            Tl[tx * 4 + 1][k] = (bf16)v.y;
            Tl[tx * 4 + 2][k] = (bf16)v.z;
            Tl[tx * 4 + 3][k] = (bf16)v.w;
        }
        __syncthreads();
        for (int pass = 0; pass < 4; ++pass) {
            int n = ty + pass * 16;
            bf16x4 ov = *(const bf16x4*)&Tl[n][tx * 4];
            *(bf16x4*)&out[(size_t)(n0 + n) * DIM + k0 + tx * 4] = ov;
        }
    }
}

// ---------------------------------------------------------------------------
// proj_fused: 128x64 tiles (M=128, N=64), BK=64, XOR-swizzled async staging,
// m-minor block mapping. LDS 48 KB -> 3 blocks/CU. Grid 1536 = 6/CU in two
// full rounds, 3 waves/SIMD. Wave grid 2x2, wave tile 64x32, acc[4][2].
// blocks [0,512):    Q proj -> Qp head layout [b,h,q,64], PRE-SCALED by
//                    SC = 1/(sqrt(64)*0.1)*log2(e) so attn S is exp2-ready.
// blocks [512,1536): KV proj: n<512 -> Kp head layout; n>=512 -> Vpt
//                    [b,h,d,1024] via in-LDS transpose (coalesced stores).
// ---------------------------------------------------------------------------
__global__ __launch_bounds__(256) void proj_fused(
    const bf16* __restrict__ Qb, const bf16* __restrict__ Kb,
    const bf16* __restrict__ Wt,
    const float* __restrict__ bq, const float* __restrict__ bk,
    const float* __restrict__ bv,
    bf16* __restrict__ Qp, bf16* __restrict__ Kp, bf16* __restrict__ Vpt)
{
    // 48 KB: A0(16K) | A1(16K) | B0(8K) | B1(8K)   (bf16 units: 8192|8192|4096|4096)
    __shared__ __attribute__((aligned(16))) bf16 sh[24576];
    const int t = threadIdx.x;
    const int wave = t >> 6, lane = t & 63, quad = lane >> 4, l16 = lane & 15;
    const int wr = wave >> 1, wc = wave & 1;
    const int bid = blockIdx.x;
    const bool isQ = bid < 512;
    const bf16* A; const bf16* W; int m0, n0;
    if (isQ) { A = Qb; W = Wt;             m0 = (bid & 63) * 128;  n0 = (bid >> 6) * 64; }
    else     { int b2 = bid - 512;
               A = Kb; W = Wt + 512 * DIM; m0 = (b2 & 63) * 128;   n0 = (b2 >> 6) * 64; }

    const int r1 = t >> 3, s1 = t & 7;
    const int p1 = s1 ^ (r1 & 7);          // rows r1+32j keep row&7
    const bf16* aSrc = A + (size_t)(m0 + r1) * DIM + p1 * 8;
    const bf16* wSrc = W + (size_t)(n0 + r1) * DIM + p1 * 8;

    floatx4 acc[4][2];
    for (int i = 0; i < 4; ++i)
        for (int j = 0; j < 2; ++j) acc[i][j] = (floatx4){0.f, 0.f, 0.f, 0.f};

    // prologue: issue kt=0 into buf 0
    #pragma unroll
    for (int j = 0; j < 4; ++j)
        async16(aSrc + (size_t)j * 32 * DIM, sh + (t + j * 256) * 8);
    #pragma unroll
    for (int j = 0; j < 2; ++j)
        async16(wSrc + (size_t)j * 32 * DIM, sh + 16384 + (t + j * 256) * 8);

    for (int kt = 0; kt < 8; ++kt) {
        __syncthreads();   // tile kt loads done; all waves done with other buf
        const int cur = kt & 1;
        bf16* Acur = sh + cur * 8192;
        bf16* Bcur = sh + 16384 + cur * 4096;
        if (kt < 7) {
            bf16* Anxt = sh + (1 - cur) * 8192;
            bf16* Bnxt = sh + 16384 + (1 - cur) * 4096;
            const int ko = (kt + 1) * 64;
            #pragma unroll
            for (int j = 0; j < 4; ++j)
                async16(aSrc + ko + (size_t)j * 32 * DIM, Anxt + (t + j * 256) * 8);
            #pragma unroll
            for (int j = 0; j < 2; ++j)
                async16(wSrc + ko + (size_t)j * 32 * DIM, Bnxt + (t + j * 256) * 8);
        }
        #pragma unroll
        for (int ks = 0; ks < 2; ++ks) {
            bf16x8 af[4], bfr[2];
            #pragma unroll
            for (int mi = 0; mi < 4; ++mi) {
                const int row = wr * 64 + mi * 16 + l16;
                af[mi] = *(const bf16x8*)(Acur + row * 64 + (((ks * 4 + quad) ^ (row & 7)) << 3));
            }
            #pragma unroll
            for (int ni = 0; ni < 2; ++ni) {
                const int row = wc * 32 + ni * 16 + l16;
                bfr[ni] = *(const bf16x8*)(Bcur + row * 64 + (((ks * 4 + quad) ^ (row & 7)) << 3));
            }
            #pragma unroll
            for (int mi = 0; mi < 4; ++mi)
                #pragma unroll
                for (int ni = 0; ni < 2; ++ni)
                    acc[mi][ni] = __builtin_amdgcn_mfma_f32_16x16x32_bf16(
                        af[mi], bfr[ni], acc[mi][ni], 0, 0, 0);
        }
    }

    const bool isV = (!isQ) && (n0 >= 512);
    if (!isV) {
        bf16* out = isQ ? Qp : Kp;
        const float* bias = isQ ? bq : bk;
        const float qscale = isQ ? 1.8033688f : 1.0f;   // SC folded into Qp
        for (int ni = 0; ni < 2; ++ni) {
            const int n = n0 + wc * 32 + ni * 16 + l16;
            const float bb = bias[n];
            const int hd = n >> 6, d = n & 63;
            for (int mi = 0; mi < 4; ++mi) {
                for (int r = 0; r < 4; ++r) {
                    const int m = m0 + wr * 64 + mi * 16 + quad * 4 + r;
                    const int b = m >> 10, q = m & 1023;
                    out[((size_t)(b * 8 + hd) * 1024 + q) * 64 + d] =
                        (bf16)((acc[mi][ni][r] + bb) * qscale);
                }
            }
        }
    } else {
        // dump tile (+bias) to LDS as Tb[n][m] (n local 0..63, 16 KB) with
        // chunk-XOR swizzle, then store coalesced rows of Vpt [b,h,d,1024]
        __syncthreads();
        for (int ni = 0; ni < 2; ++ni) {
            const int n = wc * 32 + ni * 16 + l16;           // local n 0..63
            const float bb = bv[n0 + n - 512];
            for (int mi = 0; mi < 4; ++mi) {
                const int mb = wr * 64 + mi * 16 + quad * 4;  // local m base (r=0..3)
                const int slot = ((mb >> 3) ^ (n & 15));
                bf16x4 pk = {(bf16)(acc[mi][ni][0] + bb), (bf16)(acc[mi][ni][1] + bb),
                             (bf16)(acc[mi][ni][2] + bb), (bf16)(acc[mi][ni][3] + bb)};
                *(bf16x4*)(sh + n * 128 + slot * 8 + (mb & 7)) = pk;
            }
        }
        __syncthreads();
        const int n = t >> 2, hf = t & 3;                     // 4 threads/row
        const int nv = n0 + n - 512, hd = nv >> 6, d = nv & 63;
        const int b = m0 >> 10, qb = m0 & 1023;
        bf16* dst = Vpt + ((size_t)(b * 8 + hd) * 64 + d) * 1024 + qb;
        #pragma unroll
        for (int j = 0; j < 4; ++j) {
            const int ch = hf * 4 + j;                        // 16 chunks of 8 m
            const int slot = ch ^ (n & 15);
            bf16x8 v8 = *(const bf16x8*)(sh + n * 128 + slot * 8);
            *(bf16x8*)(dst + ch * 8) = v8;
        }
    }
}

// ---------------------------------------------------------------------------
// attn: flash attention per (b,h). 1024 blocks x 4 waves, 64 q/block,
// 16 q/wave (4096 waves, LDS 40KB -> 4 blocks/CU). 16x16x32 MFMA, S^T
// trick (A=K, B=Q). Q pre-scaled in proj -> P = exp2(S) directly.
// Mask: 1-load + __all ballot fast path (uniform branch).
// Denominator: mfma(P, ones) row-sum on the matrix pipe (no VALU adds,
// no epilogue shuffles). K/V LDS double-buffer via global_load_lds.
// [round-4 verified best; x16 in-reg-P variant (r7) was net-negative:
//  K=16 MFMAs double matrix-pipe issue, eating the LDS savings.]
// ---------------------------------------------------------------------------
__global__ __launch_bounds__(256) void attn_kernel(
    const bf16* __restrict__ Qp, const bf16* __restrict__ Kp,
    const bf16* __restrict__ Vpt, const int* __restrict__ mask,
    bf16* __restrict__ Oa)
{
    const int bh = blockIdx.x & 63, qblk = blockIdx.x >> 6;  // qblk 0..15
    const int b = bh >> 3, hd = bh & 7;
    const int t = threadIdx.x;
    const int wave = t >> 6, lane = t & 63, quad = lane >> 4, l16 = lane & 15;

    __shared__ __attribute__((aligned(16))) bf16 Kt[2][64 * 64];
    __shared__ __attribute__((aligned(16))) bf16 Vt[2][64 * 64];
    __shared__ __attribute__((aligned(16))) bf16 Pl[4][16 * 64];

    const bf16* Qbase = Qp + ((size_t)bh * NQ + qblk * 64 + wave * 16) * DH;
    const bf16* Kbase = Kp + (size_t)bh * NK * DH;
    const bf16* Vbase = Vpt + (size_t)bh * DH * NK;
    const int* mrow = mask + b * NK;

    // Q B-frags (col=q=l16, k = hh*32 + quad*8 + j), kept in regs
    bf16x8 qf[2];
    #pragma unroll
    for (int hh = 0; hh < 2; ++hh)
        qf[hh] = *(const bf16x8*)(Qbase + (size_t)l16 * DH + hh * 32 + quad * 8);

    // all-ones B-frag for the denominator row-sum MFMA
    bf16x8 onesv;
    #pragma unroll
    for (int j = 0; j < 8; ++j) onesv[j] = (bf16)1.0f;

    floatx4 o[4];
    floatx4 osum = (floatx4){0.f, 0.f, 0.f, 0.f};
    #pragma unroll
    for (int i = 0; i < 4; ++i) o[i] = (floatx4){0.f, 0.f, 0.f, 0.f};

    const int r1 = t >> 3, s1 = t & 7;
    const int p1 = s1 ^ (r1 & 7);          // (r1+32)&7 == r1&7
    const bf16* kSrc = Kbase + r1 * 64 + p1 * 8;            // + kt*4096
    const bf16* vSrc = Vbase + (size_t)r1 * 1024 + p1 * 8;  // + kt*64

    // prologue: issue tile 0 into buf 0
    async16(kSrc, Kt[0] + t * 8);
    async16(kSrc + 32 * 64, Kt[0] + (t + 256) * 8);
    async16(vSrc, Vt[0] + t * 8);
    async16(vSrc + (size_t)32 * 1024, Vt[0] + (t + 256) * 8);

    for (int kt = 0; kt < NK / 64; ++kt) {
        __syncthreads();   // tile kt loads complete; all waves done with other buf
        const int cur = kt & 1;
        if (kt < NK / 64 - 1) {
            const int nxt = 1 - cur;
            async16(kSrc + (kt + 1) * 4096, Kt[nxt] + t * 8);
            async16(kSrc + (kt + 1) * 4096 + 32 * 64, Kt[nxt] + (t + 256) * 8);
            async16(vSrc + (kt + 1) * 64, Vt[nxt] + t * 8);
            async16(vSrc + (kt + 1) * 64 + (size_t)32 * 1024, Vt[nxt] + (t + 256) * 8);
        }

        // K A-frags (lane = key-within-subtile), conflict-free quad-spread
        bf16x8 kb[4][2];
        #pragma unroll
        for (int sub = 0; sub < 4; ++sub) {
            const int rowk = sub * 16 + l16;
            kb[sub][0] = *(const bf16x8*)(Kt[cur] + rowk * 64 + ((quad ^ (rowk & 7)) << 3));
            kb[sub][1] = *(const bf16x8*)(Kt[cur] + rowk * 64 + (((quad + 4) ^ (rowk & 7)) << 3));
        }
        // S^T = K Q^T: C col = q (l16), row = key-within-sub (quad*4+r)
        floatx4 sf[4];
        __builtin_amdgcn_s_setprio(1);
        #pragma unroll
        for (int sub = 0; sub < 4; ++sub) {
            floatx4 s = {0.f, 0.f, 0.f, 0.f};
            s = __builtin_amdgcn_mfma_f32_16x16x32_bf16(kb[sub][0], qf[0], s, 0, 0, 0);
            s = __builtin_amdgcn_mfma_f32_16x16x32_bf16(kb[sub][1], qf[1], s, 0, 0, 0);
            sf[sub] = s;
        }
        __builtin_amdgcn_s_setprio(0);

        // mask: wave-uniform fast path (1 dword/lane + ballot per 64-key tile)
        const int mv = mrow[kt * 64 + lane];
        if (!__all(mv != 0)) {
            #pragma unroll
            for (int sub = 0; sub < 4; ++sub) {
                const int4 m4 = *(const int4*)&mrow[kt * 64 + sub * 16 + quad * 4];
                if (!m4.x) sf[sub][0] = -3.0e38f;
                if (!m4.y) sf[sub][1] = -3.0e38f;
                if (!m4.z) sf[sub][2] = -3.0e38f;
                if (!m4.w) sf[sub][3] = -3.0e38f;
            }
        }
        // P = exp2(S') (scale pre-folded into Qp)
        #pragma unroll
        for (int sub = 0; sub < 4; ++sub) {
            sf[sub][0] = __builtin_amdgcn_exp2f(sf[sub][0]);
            sf[sub][1] = __builtin_amdgcn_exp2f(sf[sub][1]);
            sf[sub][2] = __builtin_amdgcn_exp2f(sf[sub][2]);
            sf[sub][3] = __builtin_amdgcn_exp2f(sf[sub][3]);
        }
        // P -> Pl[q][key]: packed b64 writes, XOR part-swizzle
        #pragma unroll
        for (int sub = 0; sub < 4; ++sub) {
            bf16x4 pk = {(bf16)sf[sub][0], (bf16)sf[sub][1],
                         (bf16)sf[sub][2], (bf16)sf[sub][3]};
            const int slot = (sub * 2 + (quad >> 1)) ^ (l16 & 7);
            *(bf16x4*)&Pl[wave][l16 * 64 + slot * 8 + (quad & 1) * 4] = pk;
        }
        bf16x8 af[2];
        #pragma unroll
        for (int hh = 0; hh < 2; ++hh) {
            const int slot = (hh * 4 + quad) ^ (l16 & 7);
            af[hh] = *(const bf16x8*)&Pl[wave][l16 * 64 + slot * 8];
        }
        // O += P V; denominator via mfma(P, ones) on the same pipe
        __builtin_amdgcn_s_setprio(1);
        osum = __builtin_amdgcn_mfma_f32_16x16x32_bf16(af[0], onesv, osum, 0, 0, 0);
        osum = __builtin_amdgcn_mfma_f32_16x16x32_bf16(af[1], onesv, osum, 0, 0, 0);
        #pragma unroll
        for (int dsub = 0; dsub < 4; ++dsub) {
            const int rowd = dsub * 16 + l16;
            bf16x8 v0 = *(const bf16x8*)(Vt[cur] + rowd * 64 + ((quad ^ (rowd & 7)) << 3));
            bf16x8 v1 = *(const bf16x8*)(Vt[cur] + rowd * 64 + (((quad + 4) ^ (rowd & 7)) << 3));
            o[dsub] = __builtin_amdgcn_mfma_f32_16x16x32_bf16(af[0], v0, o[dsub], 0, 0, 0);
            o[dsub] = __builtin_amdgcn_mfma_f32_16x16x32_bf16(af[1], v1, o[dsub], 0, 0, 0);
        }
        __builtin_amdgcn_s_setprio(0);
    }

    // osum[r] = full denominator for q = quad*4 + r (replicated over l16)
    float linv[4];
    #pragma unroll
    for (int r = 0; r < 4; ++r) linv[r] = 1.f / osum[r];
    for (int dsub = 0; dsub < 4; ++dsub) {
        for (int r = 0; r < 4; ++r) {
            const int q = qblk * 64 + wave * 16 + quad * 4 + r;
            const int col = hd * 64 + dsub * 16 + l16;
            Oa[((size_t)(b * NQ + q)) * DIM + col] = (bf16)(o[dsub][r] * linv[r]);
        }
    }
}

// ---------------------------------------------------------------------------
// ffn_gemm: 128x64 tiles (M=128, N=64), BK=64, XOR-swizzled staging,
// m-minor mapping, K-loop double-buffer. Grid 512, LDS 64 KB (A0|A1|B0|B1|R).
// Yb (bf16) = Oa + relu(Oa @ Wo^T + bo).
// RESIDUAL FROM LDS: the output tile Oa[m0..+128][n0..+64] equals the staged
// A-tile at kt == n0>>6 (A's k-space == output n-space). Stash that buffer
// into R (16 KB) and read the residual from LDS in the epilogue instead of
// 32 scattered scalar global loads per thread.
// ---------------------------------------------------------------------------
__global__ __launch_bounds__(256) void ffn_gemm(
    const bf16* __restrict__ Oa, const bf16* __restrict__ W,
    const float* __restrict__ bias, bf16* __restrict__ Yb)
{
    __shared__ __attribute__((aligned(16))) bf16 sh[32768];  // 64 KB
    const int t = threadIdx.x;
    const int wave = t >> 6, lane = t & 63, quad = lane >> 4, l16 = lane & 15;
    const int wr = wave >> 1, wc = wave & 1;
    const int m0 = (blockIdx.x & 63) * 128, n0 = (blockIdx.x >> 6) * 64;
    const int ktr = n0 >> 6;               // K-iter whose A-tile == residual tile

    const int r1 = t >> 3, s1 = t & 7;
    const int p1 = s1 ^ (r1 & 7);
    const bf16* aSrc = Oa + (size_t)(m0 + r1) * DIM + p1 * 8;
    const bf16* wSrc = W  + (size_t)(n0 + r1) * DIM + p1 * 8;

    floatx4 acc[4][2];
    for (int i = 0; i < 4; ++i)
        for (int j = 0; j < 2; ++j) acc[i][j] = (floatx4){0.f, 0.f, 0.f, 0.f};

    #pragma unroll
    for (int j = 0; j < 4; ++j)
        async16(aSrc + (size_t)j * 32 * DIM, sh + (t + j * 256) * 8);
    #pragma unroll
    for (int j = 0; j < 2; ++j)
        async16(wSrc + (size_t)j * 32 * DIM, sh + 16384 + (t + j * 256) * 8);

    for (int kt = 0; kt < 8; ++kt) {
        __syncthreads();
        const int cur = kt & 1;
        bf16* Acur = sh + cur * 8192;
        bf16* Bcur = sh + 16384 + cur * 4096;
        if (kt < 7) {
            bf16* Anxt = sh + (1 - cur) * 8192;
            bf16* Bnxt = sh + 16384 + (1 - cur) * 4096;
            const int ko = (kt + 1) * 64;
            #pragma unroll
            for (int j = 0; j < 4; ++j)
                async16(aSrc + ko + (size_t)j * 32 * DIM, Anxt + (t + j * 256) * 8);
            #pragma unroll
            for (int j = 0; j < 2; ++j)
                async16(wSrc + ko + (size_t)j * 32 * DIM, Bnxt + (t + j * 256) * 8);
        }
        if (kt == ktr) {   // stash residual tile (uniform branch, once/block)
            #pragma unroll
            for (int j = 0; j < 4; ++j) {
                const int idx = t + j * 256;
                *(bf16x8*)(sh + 24576 + idx * 8) = *(const bf16x8*)(Acur + idx * 8);
            }
        }
        #pragma unroll
        for (int ks = 0; ks < 2; ++ks) {
            bf16x8 af[4], bfr[2];
            #pragma unroll
            for (int mi = 0; mi < 4; ++mi) {
                const int row = wr * 64 + mi * 16 + l16;
                af[mi] = *(const bf16x8*)(Acur + row * 64 + (((ks * 4 + quad) ^ (row & 7)) << 3));
            }
            #pragma unroll
            for (int ni = 0; ni < 2; ++ni) {
                const int row = wc * 32 + ni * 16 + l16;
                bfr[ni] = *(const bf16x8*)(Bcur + row * 64 + (((ks * 4 + quad) ^ (row & 7)) << 3));
            }
            #pragma unroll
            for (int mi = 0; mi < 4; ++mi)
                #pragma unroll
                for (int ni = 0; ni < 2; ++ni)
                    acc[mi][ni] = __builtin_amdgcn_mfma_f32_16x16x32_bf16(
                        af[mi], bfr[ni], acc[mi][ni], 0, 0, 0);
        }
    }
    __syncthreads();       // R complete (covers ktr == 7)

    for (int ni = 0; ni < 2; ++ni) {
        const int n = n0 + wc * 32 + ni * 16 + l16;
        const int cl = wc * 32 + ni * 16 + l16;          // local col in R
        const int chi = cl >> 3, clo = cl & 7;
        const float bb = bias[n];
        for (int mi = 0; mi < 4; ++mi) {
            for (int r = 0; r < 4; ++r) {
                const int rl = wr * 64 + mi * 16 + quad * 4 + r;   // local row
                const float ov = (float)sh[24576 + rl * 64 + ((chi ^ (rl & 7)) << 3) + clo];
                Yb[(size_t)(m0 + rl) * DIM + n] = (bf16)(ov + fmaxf(acc[mi][ni][r] + bb, 0.f));
            }
        }
    }
}

// ---------------------------------------------------------------------------
// ln: LayerNorm over last dim (512). One wave per row; bf16 in, fp32 out.
// ---------------------------------------------------------------------------
__global__ __launch_bounds__(256) void ln_kernel(
    const bf16* __restrict__ Y, const float* __restrict__ gamma,
    const float* __restrict__ beta, float* __restrict__ out)
{
    const int row  = blockIdx.x * 4 + (threadIdx.x >> 6);
    const int lane = threadIdx.x & 63;
    bf16x8 v = *(const bf16x8*)(Y + (size_t)row * DIM + lane * 8);
    float f[8];
    float s = 0.f, sq = 0.f;
    #pragma unroll
    for (int j = 0; j < 8; ++j) {
        f[j] = (float)v[j];
        s += f[j];
        sq += f[j] * f[j];
    }
    for (int mk = 32; mk >= 1; mk >>= 1) {
        s  += __shfl_xor(s,  mk, 64);
        sq += __shfl_xor(sq, mk, 64);
    }
    const float mu  = s * (1.f / 512.f);
    const float var = sq * (1.f / 512.f) - mu * mu;
    const float inv = rsqrtf(var + 1e-5f);
    float4 g1 = ((const float4*)gamma)[lane * 2];
    float4 g2 = ((const float4*)gamma)[lane * 2 + 1];
    float4 b1 = ((const float4*)beta)[lane * 2];
    float4 b2 = ((const float4*)beta)[lane * 2 + 1];
    float4 o1, o2;
    o1.x = (f[0] - mu) * inv * g1.x + b1.x;
    o1.y = (f[1] - mu) * inv * g1.y + b1.y;
    o1.z = (f[2] - mu) * inv * g1.z + b1.z;
    o1.w = (f[3] - mu) * inv * g1.w + b1.w;
    o2.x = (f[4] - mu) * inv * g2.x + b2.x;
    o2.y = (f[5] - mu) * inv * g2.y + b2.y;
    o2.z = (f[6] - mu) * inv * g2.z + b2.z;
    o2.w = (f[7] - mu) * inv * g2.w + b2.w;
    float* orow = out + (size_t)row * DIM;
    ((float4*)orow)[lane * 2]     = o1;
    ((float4*)orow)[lane * 2 + 1] = o2;
}

// ---------------------------------------------------------------------------
extern "C" void kernel_launch(void* const* d_in, const int* in_sizes, int n_in,
                              void* d_out, int out_size, void* d_ws, size_t ws_size,
                              hipStream_t stream) {
    const float* Q  = (const float*)d_in[0];
    const float* K  = (const float*)d_in[1];
    const int*   mask = (const int*)d_in[2];
    const float* Wq = (const float*)d_in[3];
    const float* bq = (const float*)d_in[4];
    const float* Wk = (const float*)d_in[5];
    const float* bk = (const float*)d_in[6];
    const float* Wv = (const float*)d_in[7];
    const float* bv = (const float*)d_in[8];
    const float* Wo = (const float*)d_in[9];
    const float* bo = (const float*)d_in[10];
    const float* gamma = (const float*)d_in[11];
    const float* beta  = (const float*)d_in[12];

    char* ws = (char*)d_ws;
    bf16* Wt  = (bf16*)(ws);                   // 2 MB (4 x 512x512 bf16, transposed)
    bf16* Qb  = (bf16*)(ws + 2097152);         // 8 MB
    bf16* Kb  = (bf16*)(ws + 10485760);        // 8 MB
    bf16* Qp  = (bf16*)(ws + 18874368);        // 8 MB  [b,h,q,64] (pre-scaled)
    bf16* Kp  = (bf16*)(ws + 27262976);        // 8 MB  [b,h,k,64]
    bf16* Vpt = (bf16*)(ws + 35651584);        // 8 MB  [b,h,d,1024]
    bf16* Oa  = (bf16*)(ws + 44040192);        // 8 MB  [b,q,512]
    bf16* Yb  = (bf16*)(ws + 52428800);        // 8 MB  [b,q,512] bf16
    float* out = (float*)d_out;

    prep_fused<<<4352, 256, 0, stream>>>(Q, K, Wq, Wk, Wv, Wo, Qb, Kb, Wt);
    proj_fused<<<1536, 256, 0, stream>>>(Qb, Kb, Wt, bq, bk, bv, Qp, Kp, Vpt);
    attn_kernel<<<1024, 256, 0, stream>>>(Qp, Kp, Vpt, mask, Oa);
    ffn_gemm<<<512, 256, 0, stream>>>(Oa, Wt + 3 * 262144, bo, Yb);
    ln_kernel<<<2048, 256, 0, stream>>>(Yb, gamma, beta, out);
}